// Round 1
// baseline (710.528 us; speedup 1.0000x reference)
//
#include <hip/hip_runtime.h>

#define W_    256
#define H_    128
#define HW_   32768
#define NB    4
#define NA    5
#define NC    64
#define NIMG  20
#define EPS_  1e-6f

// ---------- bilinear warp taps (matches reference affine_grid + grid_sample) ----------
struct Taps { int o00,o01,o10,o11; float w00,w01,w10,w11; };

__device__ inline Taps make_taps(const float* __restrict__ M, int h, int w){
  float gx = 2.0f*((float)w+0.5f)/(float)W_ - 1.0f;
  float gy = 2.0f*((float)h+0.5f)/(float)H_ - 1.0f;
  float X = M[0]*gx + M[1]*gy + M[2];
  float Y = M[3]*gx + M[4]*gy + M[5];
  float px = ((X+1.0f)*(float)W_ - 1.0f)*0.5f;
  float py = ((Y+1.0f)*(float)H_ - 1.0f)*0.5f;
  float x0f = floorf(px), y0f = floorf(py);
  float wx1 = px-x0f, wy1 = py-y0f;
  float wx0 = 1.0f-wx1, wy0 = 1.0f-wy1;
  int x0=(int)x0f, y0=(int)y0f, x1=x0+1, y1=y0+1;
  bool vx0=(x0>=0)&&(x0<W_), vx1=(x1>=0)&&(x1<W_);
  bool vy0=(y0>=0)&&(y0<H_), vy1=(y1>=0)&&(y1<H_);
  int cx0=min(max(x0,0),W_-1), cx1=min(max(x1,0),W_-1);
  int cy0=min(max(y0,0),H_-1), cy1=min(max(y1,0),H_-1);
  Taps t;
  t.o00=cy0*W_+cx0; t.o01=cy0*W_+cx1; t.o10=cy1*W_+cx0; t.o11=cy1*W_+cx1;
  t.w00=(vy0&&vx0)?(wy0*wx0):0.f;
  t.w01=(vy0&&vx1)?(wy0*wx1):0.f;
  t.w10=(vy1&&vx0)?(wy1*wx0):0.f;
  t.w11=(vy1&&vx1)?(wy1*wx1):0.f;
  return t;
}

__device__ inline float clip01(float v){ return fminf(fmaxf(v,0.f),1.f); }
__device__ inline float sigmoidf_(float v){
  if (v>=0.f){ float e=expf(-v); return 1.f/(1.f+e); }
  float e=expf(v); return e/(1.f+e);
}
// reference masked_quantile interpolation: vlo + frac*(vhi-vlo), 0 if cnt==0
__device__ inline float quantv(int cnt, float q, float vlo, float vhi){
  if (cnt<=0) return 0.f;
  float pos = q*(float)(cnt-1);
  float frac = pos - floorf(pos);
  return vlo + frac*(vhi-vlo);
}
__device__ inline float ge_f(float t, float lo, float hi){
  return clip01((t-lo)/(hi-lo+EPS_));
}

// ---------- K0: zero the effective-rate counter ----------
__global__ void k_init(int* counter){ if (threadIdx.x==0) *counter = 0; }

// ---------- K1: fused warp of ones/psm/x -> vis, scraw(=comm_map), sfull, energy ----------
__global__ __launch_bounds__(256) void k_warp_stats(
  const float* __restrict__ x, const float* __restrict__ psm, const float* __restrict__ nam,
  float* __restrict__ vis, float* __restrict__ scraw, float* __restrict__ sfull,
  float* __restrict__ energy)
{
  int w = threadIdx.x, h = blockIdx.x, bn = blockIdx.y;
  int b = bn/NA, n = bn - b*NA;
  Taps t = make_taps(nam + (size_t)(b*NA*NA + n)*6, h, w);     // M = nam[b,0,n]
  float vv = t.w00 + t.w01 + t.w10 + t.w11;                    // warp of ones
  const float* p0 = psm + ((size_t)bn*2+0)*HW_;
  const float* p1 = psm + ((size_t)bn*2+1)*HW_;
  float c0 = t.w00*p0[t.o00] + t.w01*p0[t.o01] + t.w10*p0[t.o10] + t.w11*p0[t.o11];
  float c1 = t.w00*p1[t.o00] + t.w01*p1[t.o01] + t.w10*p1[t.o10] + t.w11*p1[t.o11];
  float sr = fmaxf(sigmoidf_(c0), sigmoidf_(c1));              // comm_map / S_c_raw
  float sf = (clip01(c0)+clip01(c1))*0.5f;                     // mean clipped conf
  const float* xb = x + (size_t)bn*NC*HW_;
  float acc = 0.f;
  #pragma unroll 8
  for (int c=0;c<NC;++c){
    const float* pc = xb + (size_t)c*HW_;
    float v = t.w00*pc[t.o00] + t.w01*pc[t.o01] + t.w10*pc[t.o10] + t.w11*pc[t.o11];
    acc += v*v;
  }
  size_t idx = (size_t)bn*HW_ + h*W_ + w;
  vis[idx]=vv; scraw[idx]=sr; sfull[idx]=sf; energy[idx]=acc*(1.0f/64.0f);
}

// ---------- K3: exact order statistics via 4x8-bit radix select ----------
// ranks: [l2,h2,l8,h8, cm1-l2,cm1-h2,cm1-l8,cm1-h8]  (reversed ranks for monotone-
// decreasing derived quantiles; only computed for ego images when nrank_full!=0)
#define OS_T 1024
__global__ __launch_bounds__(1024) void k_order_stats(
    const float* __restrict__ data, const float* __restrict__ mask,
    int data_stride, int mask_stride, int nrank_full, float* __restrict__ stats)
{
  __shared__ int hist[256*16];
  __shared__ int cum[256];
  __shared__ int cum0[256];
  __shared__ int s_cnt;
  __shared__ int s_sel, s_rk;
  int img = blockIdx.x, tid = threadIdx.x;
  const float* d = data + (size_t)img*data_stride;
  const float* m = mask + (size_t)img*mask_stride;
  int slice = tid & 15;
  if (tid==0) s_cnt = 0;
  for (int i=tid;i<256*16;i+=OS_T) hist[i]=0;
  __syncthreads();
  // count + round-0 histogram (top byte of sortable key) in one pass
  int c = 0;
  for (int i=tid;i<HW_;i+=OS_T){
    unsigned u = __float_as_uint(d[i]);
    unsigned key = (u & 0x80000000u) ? ~u : (u|0x80000000u);
    if (m[i] > 0.f) ++c; else key = 0xFFFFFFFFu;
    atomicAdd(&hist[((key>>24)<<4) + slice], 1);
  }
  for (int off=32;off;off>>=1) c += __shfl_down(c, off);
  if ((tid&63)==0) atomicAdd(&s_cnt, c);
  __syncthreads();
  if (tid<256){
    int tt=0;
    #pragma unroll
    for (int j=0;j<16;++j) tt += hist[(tid<<4)+j];
    cum[tid]=tt;
  }
  __syncthreads();
  for (int off=1;off<256;off<<=1){
    int v = (tid<256 && tid>=off)?cum[tid-off]:0;
    __syncthreads();
    if (tid<256) cum[tid]+=v;
    __syncthreads();
  }
  if (tid<256) cum0[tid]=cum[tid];
  __syncthreads();
  int cnt = s_cnt;
  int cm1 = cnt>0 ? cnt-1 : 0;
  float pos2 = 0.2f*(float)cm1, pos8 = 0.8f*(float)cm1;
  int l2=(int)floorf(pos2), h2=(int)ceilf(pos2);
  int l8=(int)floorf(pos8), h8=(int)ceilf(pos8);
  int rk8[8] = {l2,h2,l8,h8, cm1-l2,cm1-h2,cm1-l8,cm1-h8};
  int nrank = nrank_full ? ((img % NA)==0 ? 8 : 4) : 4;
  if (tid==0) stats[img*16] = (float)cnt;
  for (int r=0;r<nrank;++r){
    int rk = rk8[r];
    // round 0: pick bin from memoized cum0
    if (tid<256){
      int below = tid?cum0[tid-1]:0;
      if (rk>=below && rk<cum0[tid]){ s_sel=tid; s_rk=rk-below; }
    }
    __syncthreads();
    unsigned pre = (unsigned)s_sel; rk = s_rk;
    __syncthreads();
    for (int round=1; round<4; ++round){
      int shift = 24-8*round;
      for (int i=tid;i<256*16;i+=OS_T) hist[i]=0;
      __syncthreads();
      for (int i=tid;i<HW_;i+=OS_T){
        unsigned u = __float_as_uint(d[i]);
        unsigned key = (u&0x80000000u)?~u:(u|0x80000000u);
        if (!(m[i]>0.f)) key = 0xFFFFFFFFu;
        if ((key>>(shift+8)) == pre)
          atomicAdd(&hist[(((key>>shift)&255u)<<4)+slice],1);
      }
      __syncthreads();
      if (tid<256){
        int tt=0;
        #pragma unroll
        for (int j=0;j<16;++j) tt += hist[(tid<<4)+j];
        cum[tid]=tt;
      }
      __syncthreads();
      for (int off=1;off<256;off<<=1){
        int v = (tid<256 && tid>=off)?cum[tid-off]:0;
        __syncthreads();
        if (tid<256) cum[tid]+=v;
        __syncthreads();
      }
      if (tid<256){
        int below = tid?cum[tid-1]:0;
        if (rk>=below && rk<cum[tid]){ s_sel=tid; s_rk=rk-below; }
      }
      __syncthreads();
      pre = (pre<<8)|(unsigned)s_sel; rk = s_rk;
      __syncthreads();
    }
    if (tid==0){
      unsigned u = (pre & 0x80000000u) ? (pre & 0x7FFFFFFFu) : ~pre;
      stats[img*16 + 1 + r] = __uint_as_float(u);
    }
  }
}

// ---------- K4: per-batch scalar params from order stats ----------
// params[b][0..4]=qe20[n] [5..9]=qe80 [10..14]=qc20 [15..19]=qc80
//          [20]=de_lo [21]=de_hi [22]=dc_lo [23]=dc_hi [24]=ke_thr [25]=kc_thr
__global__ void k_params(const float* __restrict__ statsE, const float* __restrict__ statsC,
                         float* __restrict__ params){
  int b = threadIdx.x;
  if (b>=NB) return;
  float* pr = params + b*32;
  for (int n=0;n<NA;++n){
    const float* sE = statsE + (size_t)(b*NA+n)*16;
    const float* sC = statsC + (size_t)(b*NA+n)*16;
    int cE=(int)sE[0], cC=(int)sC[0];
    pr[n]    = quantv(cE,0.2f,sE[1],sE[2]);
    pr[5+n]  = quantv(cE,0.8f,sE[3],sE[4]);
    pr[10+n] = quantv(cC,0.2f,sC[1],sC[2]);
    pr[15+n] = quantv(cC,0.8f,sC[3],sC[4]);
  }
  const float* sE0 = statsE + (size_t)(b*NA)*16;
  const float* sC0 = statsC + (size_t)(b*NA)*16;
  float loe=pr[0], hie=pr[5], loc=pr[10], hic=pr[15];
  float de_lo=0.f,de_hi=0.f,ke=0.f, dc_lo=0.f,dc_hi=0.f,kc=0.f;
  int c0=(int)sE0[0];
  if (c0>0){
    int cm1=c0-1;
    float pos2=0.2f*(float)cm1, pos8=0.8f*(float)cm1;
    float f2=pos2-floorf(pos2), f8=pos8-floorf(pos8);
    float a,bb;
    a=1.f-ge_f(sE0[5],loe,hie); bb=1.f-ge_f(sE0[6],loe,hie); de_lo=a+f2*(bb-a);
    a=1.f-ge_f(sE0[7],loe,hie); bb=1.f-ge_f(sE0[8],loe,hie); de_hi=a+f8*(bb-a);
    a=ge_f(sE0[1],loe,hie);     bb=ge_f(sE0[2],loe,hie);     ke  =a+f2*(bb-a);
  }
  int c0c=(int)sC0[0];
  if (c0c>0){
    int cm1=c0c-1;
    float pos2=0.2f*(float)cm1, pos8=0.8f*(float)cm1;
    float f2=pos2-floorf(pos2), f8=pos8-floorf(pos8);
    float a,bb;
    a=1.f-ge_f(sC0[5],loc,hic); bb=1.f-ge_f(sC0[6],loc,hic); dc_lo=a+f2*(bb-a);
    a=1.f-ge_f(sC0[7],loc,hic); bb=1.f-ge_f(sC0[8],loc,hic); dc_hi=a+f8*(bb-a);
    a=ge_f(sC0[1],loc,hic);     bb=ge_f(sC0[2],loc,hic);     kc  =a+f2*(bb-a);
  }
  pr[20]=de_lo; pr[21]=de_hi; pr[22]=dc_lo; pr[23]=dc_hi; pr[24]=ke; pr[25]=kc;
}

// ---------- K5: pattern-gate P (pre-normalization) ----------
__global__ __launch_bounds__(256) void k_ppre(
  const float* __restrict__ vis, const float* __restrict__ scraw,
  const float* __restrict__ energy, const float* __restrict__ params,
  float* __restrict__ ppre)
{
  int w=threadIdx.x, h=blockIdx.x, b=blockIdx.y;
  int p=h*W_+w;
  const float* pr = params + b*32;
  size_t base = (size_t)b*NA*HW_ + p;
  float se[NA], sc[NA], vf[NA];
  #pragma unroll
  for (int n=0;n<NA;++n){
    float vv = vis[base + (size_t)n*HW_];
    float f = (vv>0.f)?1.f:0.f; vf[n]=f;
    se[n] = clip01((energy[base+(size_t)n*HW_]-pr[n])/(pr[5+n]-pr[n]+EPS_))*f;
    sc[n] = clip01((scraw[base+(size_t)n*HW_]-pr[10+n])/(pr[15+n]-pr[10+n]+EPS_))*f;
  }
  float sup = 0.f;
  #pragma unroll
  for (int n=1;n<NA;++n) sup += (0.8f*se[n]+0.2f*sc[n])*vf[n];
  sup *= 0.25f;
  float de = clip01(((1.f-se[0])-pr[20])/(pr[21]-pr[20]+EPS_))*vf[0];
  float dc = clip01(((1.f-sc[0])-pr[22])/(pr[23]-pr[22]+EPS_))*vf[0];
  float D  = (0.7f*de + 0.3f*dc)*vf[0];
  bool ke = (se[0] <= pr[24]) && (vf[0]>0.f);
  bool kc = (sc[0] <= pr[25]) && (vf[0]>0.f);
  float kem = (ke&&kc)?1.f:0.f;
  ppre[(size_t)b*HW_+p] = D*sup*(1.f-kem);
}

// ---------- K6: winner argmax + owner/comm bits ----------
__global__ __launch_bounds__(256) void k_owner(
  const float* __restrict__ vis, const float* __restrict__ scraw,
  const float* __restrict__ sfull, const float* __restrict__ ppre,
  const float* __restrict__ statsP, int* __restrict__ omask)
{
  int w=threadIdx.x,h=blockIdx.x,b=blockIdx.y;
  int p=h*W_+w;
  const float* sP = statsP + b*16;
  int cntP=(int)sP[0];
  float plo = quantv(cntP,0.2f,sP[1],sP[2]);
  float phi = quantv(cntP,0.8f,sP[3],sP[4]);
  size_t base=(size_t)b*NA*HW_+p;
  float vf0 = (vis[base]>0.f)?1.f:0.f;
  float Pf = clip01((ppre[(size_t)b*HW_+p]-plo)/(phi-plo+EPS_))*vf0;
  float gate = 0.1f + 0.9f*Pf;
  int winner=0; float best=-1.f;     // scores >= 0 -> first-max tie rule preserved
  int cbits=0;
  #pragma unroll
  for (int n=0;n<NA;++n){
    float vv = vis[base+(size_t)n*HW_];
    float f=(vv>0.f)?1.f:0.f;
    float s = ((sfull[base+(size_t)n*HW_]*f)*gate)*f;
    if (s>best){best=s;winner=n;}
    bool cm = (n==0) || (scraw[base+(size_t)n*HW_] > 0.5f);
    if (cm) cbits |= 1<<n;
  }
  int ob = ((cbits>>winner)&1) ? (1<<winner) : 0;
  omask[(size_t)b*HW_+p] = ob | (cbits<<8);
}

// ---------- K7: 3x3 dilation, final mask, effective-rate count ----------
__global__ __launch_bounds__(256) void k_final(
  const int* __restrict__ omask, int* __restrict__ fmask, int* __restrict__ counter)
{
  int w=threadIdx.x,h=blockIdx.x,b=blockIdx.y;
  int p=h*W_+w;
  const int* om = omask + (size_t)b*HW_;
  int ow=0;
  #pragma unroll
  for (int dy=-1;dy<=1;++dy){
    int y=h+dy; if (y<0||y>=H_) continue;
    #pragma unroll
    for (int dx=-1;dx<=1;++dx){
      int x=w+dx; if (x<0||x>=W_) continue;
      ow |= om[y*W_+x];
    }
  }
  int cbits=(om[p]>>8)&31;
  int fin = ow & cbits & 31;
  fmask[(size_t)b*HW_+p]=fin;
  int cn = __popc(fin & 30);
  for (int off=32;off;off>>=1) cn += __shfl_down(cn,off);
  if ((threadIdx.x&63)==0) atomicAdd(counter, cn);
}

// ---------- K8: masked-max warped output + effective rate ----------
__global__ __launch_bounds__(256) void k_out(
  const float* __restrict__ x, const float* __restrict__ nam,
  const int* __restrict__ fmask, const int* __restrict__ counter,
  float* __restrict__ out, int out_size)
{
  int w=threadIdx.x, h=blockIdx.x, b=blockIdx.y;
  int p=h*W_+w;
  int fin = fmask[(size_t)b*HW_+p] & 31;
  float init = (__popc(fin)<NA) ? 0.f : -__builtin_inff();
  float m[NC];
  #pragma unroll
  for (int c=0;c<NC;++c) m[c]=init;
  #pragma unroll
  for (int n=0;n<NA;++n){
    if (!((fin>>n)&1)) continue;
    Taps t = make_taps(nam + (size_t)(b*NA*NA+n)*6, h, w);
    const float* xb = x + (size_t)(b*NA+n)*NC*HW_;
    #pragma unroll 8
    for (int c=0;c<NC;++c){
      const float* pc = xb + (size_t)c*HW_;
      float v = t.w00*pc[t.o00] + t.w01*pc[t.o01] + t.w10*pc[t.o10] + t.w11*pc[t.o11];
      m[c] = fmaxf(m[c], v);
    }
  }
  #pragma unroll
  for (int c=0;c<NC;++c) out[(((size_t)b*NC+c)*H_+h)*W_+w] = m[c];
  if (b==0 && h==0 && w==0)
    out[out_size-1] = (float)(*counter) * (1.0f/524288.0f);  // /(B*(N-1)*H*W)
}

extern "C" void kernel_launch(void* const* d_in, const int* in_sizes, int n_in,
                              void* d_out, int out_size, void* d_ws, size_t ws_size,
                              hipStream_t stream) {
  (void)in_sizes; (void)n_in; (void)ws_size;
  const float* x   = (const float*)d_in[0];
  const float* psm = (const float*)d_in[1];
  const float* nam = (const float*)d_in[3];   // record_len (d_in[2]) unused by reference
  float* out = (float*)d_out;

  float* ws     = (float*)d_ws;
  float* vis    = ws;                         // 20*HW
  float* scraw  = vis    + (size_t)NIMG*HW_;  // 20*HW
  float* sfull  = scraw  + (size_t)NIMG*HW_;  // 20*HW
  float* energy = sfull  + (size_t)NIMG*HW_;  // 20*HW
  float* ppre   = energy + (size_t)NIMG*HW_;  // 4*HW
  float* statsE = ppre   + (size_t)NB*HW_;    // 20*16
  float* statsC = statsE + NIMG*16;           // 20*16
  float* statsP = statsC + NIMG*16;           // 4*16
  float* params = statsP + NB*16;             // 4*32
  int*   omask  = (int*)(params + NB*32);     // 4*HW
  int*   fmask  = omask + (size_t)NB*HW_;     // 4*HW
  int*   counter= fmask + (size_t)NB*HW_;     // 1

  hipLaunchKernelGGL(k_init, dim3(1), dim3(64), 0, stream, counter);
  hipLaunchKernelGGL(k_warp_stats, dim3(H_,NIMG), dim3(W_), 0, stream,
                     x, psm, nam, vis, scraw, sfull, energy);
  hipLaunchKernelGGL(k_order_stats, dim3(NIMG), dim3(OS_T), 0, stream,
                     energy, vis, HW_, HW_, 1, statsE);
  hipLaunchKernelGGL(k_order_stats, dim3(NIMG), dim3(OS_T), 0, stream,
                     scraw, vis, HW_, HW_, 1, statsC);
  hipLaunchKernelGGL(k_params, dim3(1), dim3(64), 0, stream, statsE, statsC, params);
  hipLaunchKernelGGL(k_ppre, dim3(H_,NB), dim3(W_), 0, stream,
                     vis, scraw, energy, params, ppre);
  hipLaunchKernelGGL(k_order_stats, dim3(NB), dim3(OS_T), 0, stream,
                     ppre, vis, HW_, NA*HW_, 0, statsP);
  hipLaunchKernelGGL(k_owner, dim3(H_,NB), dim3(W_), 0, stream,
                     vis, scraw, sfull, ppre, statsP, omask);
  hipLaunchKernelGGL(k_final, dim3(H_,NB), dim3(W_), 0, stream, omask, fmask, counter);
  hipLaunchKernelGGL(k_out, dim3(H_,NB), dim3(W_), 0, stream,
                     x, nam, fmask, counter, out, out_size);
}

// Round 2
// 392.266 us; speedup vs baseline: 1.8113x; 1.8113x over previous
//
#include <hip/hip_runtime.h>

#define W_    256
#define H_    128
#define HW_   32768
#define NB    4
#define NA    5
#define NC    64
#define NIMG  20
#define EPS_  1e-6f

// ---------- bilinear warp taps (matches reference affine_grid + grid_sample) ----------
struct Taps { int o00,o01,o10,o11; float w00,w01,w10,w11; };

__device__ inline Taps make_taps(const float* __restrict__ M, int h, int w){
  float gx = 2.0f*((float)w+0.5f)/(float)W_ - 1.0f;
  float gy = 2.0f*((float)h+0.5f)/(float)H_ - 1.0f;
  float X = M[0]*gx + M[1]*gy + M[2];
  float Y = M[3]*gx + M[4]*gy + M[5];
  float px = ((X+1.0f)*(float)W_ - 1.0f)*0.5f;
  float py = ((Y+1.0f)*(float)H_ - 1.0f)*0.5f;
  float x0f = floorf(px), y0f = floorf(py);
  float wx1 = px-x0f, wy1 = py-y0f;
  float wx0 = 1.0f-wx1, wy0 = 1.0f-wy1;
  int x0=(int)x0f, y0=(int)y0f, x1=x0+1, y1=y0+1;
  bool vx0=(x0>=0)&&(x0<W_), vx1=(x1>=0)&&(x1<W_);
  bool vy0=(y0>=0)&&(y0<H_), vy1=(y1>=0)&&(y1<H_);
  int cx0=min(max(x0,0),W_-1), cx1=min(max(x1,0),W_-1);
  int cy0=min(max(y0,0),H_-1), cy1=min(max(y1,0),H_-1);
  Taps t;
  t.o00=cy0*W_+cx0; t.o01=cy0*W_+cx1; t.o10=cy1*W_+cx0; t.o11=cy1*W_+cx1;
  t.w00=(vy0&&vx0)?(wy0*wx0):0.f;
  t.w01=(vy0&&vx1)?(wy0*wx1):0.f;
  t.w10=(vy1&&vx0)?(wy1*wx0):0.f;
  t.w11=(vy1&&vx1)?(wy1*wx1):0.f;
  return t;
}

__device__ inline float clip01(float v){ return fminf(fmaxf(v,0.f),1.f); }
__device__ inline float sigmoidf_(float v){
  if (v>=0.f){ float e=expf(-v); return 1.f/(1.f+e); }
  float e=expf(v); return e/(1.f+e);
}
__device__ inline float quantv(int cnt, float q, float vlo, float vhi){
  if (cnt<=0) return 0.f;
  float pos = q*(float)(cnt-1);
  float frac = pos - floorf(pos);
  return vlo + frac*(vhi-vlo);
}
__device__ inline float ge_f(float t, float lo, float hi){
  return clip01((t-lo)/(hi-lo+EPS_));
}

// ---------- K0: zero counters (effective-rate + per-image visible counts) ----------
__global__ void k_init(int* counters){ if (threadIdx.x < 1+NIMG) counters[threadIdx.x] = 0; }

// ---------- K1: fused warp of ones/psm/x -> vis, scraw, sfull, energy, vis-counts ----------
__global__ __launch_bounds__(256) void k_warp_stats(
  const float* __restrict__ x, const float* __restrict__ psm, const float* __restrict__ nam,
  float* __restrict__ vis, float* __restrict__ scraw, float* __restrict__ sfull,
  float* __restrict__ energy, int* __restrict__ cntv)
{
  int w = threadIdx.x, h = blockIdx.x, bn = blockIdx.y;
  int b = bn/NA, n = bn - b*NA;
  Taps t = make_taps(nam + (size_t)(b*NA*NA + n)*6, h, w);     // M = nam[b,0,n]
  float vv = t.w00 + t.w01 + t.w10 + t.w11;                    // warp of ones
  const float* p0 = psm + ((size_t)bn*2+0)*HW_;
  const float* p1 = psm + ((size_t)bn*2+1)*HW_;
  float c0 = t.w00*p0[t.o00] + t.w01*p0[t.o01] + t.w10*p0[t.o10] + t.w11*p0[t.o11];
  float c1 = t.w00*p1[t.o00] + t.w01*p1[t.o01] + t.w10*p1[t.o10] + t.w11*p1[t.o11];
  float sr = fmaxf(sigmoidf_(c0), sigmoidf_(c1));
  float sf = (clip01(c0)+clip01(c1))*0.5f;
  const float* xb = x + (size_t)bn*NC*HW_;
  float acc = 0.f;
  #pragma unroll 8
  for (int c=0;c<NC;++c){
    const float* pc = xb + (size_t)c*HW_;
    float v = t.w00*pc[t.o00] + t.w01*pc[t.o01] + t.w10*pc[t.o10] + t.w11*pc[t.o11];
    acc += v*v;
  }
  size_t idx = (size_t)bn*HW_ + h*W_ + w;
  vis[idx]=vv; scraw[idx]=sr; sfull[idx]=sf; energy[idx]=acc*(1.0f/64.0f);
  int vf = (vv>0.f)?1:0;
  #pragma unroll
  for (int off=32;off;off>>=1) vf += __shfl_down(vf,off);
  if ((w&63)==0) atomicAdd(&cntv[bn], vf);
}

// ---------- K3: radix-select, ONE BLOCK PER (image, rank) task ----------
// mode 0 (E+C): 192 blocks. t<96 -> energy, else scraw (t-=96).
//   tt<80: img=tt/4, r=tt%4 (ranks l2,h2,l8,h8); tt>=80: ego reversed ranks r=4..7.
// mode 1 (P): 16 blocks. img=t/4 (batch), r=t%4; mask = ego vis; cnt = ego cnt.
#define OS_T 1024
__global__ __launch_bounds__(1024) void k_select(
    const float* __restrict__ energy, const float* __restrict__ scraw,
    const float* __restrict__ ppre, const float* __restrict__ vis,
    const int* __restrict__ cnts,
    float* __restrict__ statsE, float* __restrict__ statsC, float* __restrict__ statsP,
    int mode)
{
  __shared__ int hist[16*256];
  __shared__ int cum[256];
  __shared__ unsigned s_pre;
  __shared__ int s_rk;
  int tid = threadIdx.x;
  int t = blockIdx.x;

  const float* d; const float* m; float* stats; int img, r, cnt;
  if (mode==0){
    bool isC = (t>=96); int tt = isC ? t-96 : t;
    if (tt<80){ img=tt>>2; r=tt&3; } else { int j=tt-80; img=(j>>2)*NA; r=4+(j&3); }
    d = (isC?scraw:energy) + (size_t)img*HW_;
    m = vis + (size_t)img*HW_;
    stats = isC?statsC:statsE;
    cnt = cnts[img];
  } else {
    img = t>>2; r = t&3;
    d = ppre + (size_t)img*HW_;
    m = vis + (size_t)(img*NA)*HW_;
    stats = statsP;
    cnt = cnts[img*NA];
  }
  int cm1 = cnt>0 ? cnt-1 : 0;
  float p2 = 0.2f*(float)cm1, p8 = 0.8f*(float)cm1;
  int l2=(int)floorf(p2), h2=(int)ceilf(p2), l8=(int)floorf(p8), h8=(int)ceilf(p8);
  int rank;
  switch(r){
    case 0: rank=l2; break;      case 1: rank=h2; break;
    case 2: rank=l8; break;      case 3: rank=h8; break;
    case 4: rank=cm1-l2; break;  case 5: rank=cm1-h2; break;
    case 6: rank=cm1-l8; break;  default: rank=cm1-h8; break;
  }

  // cache sortable keys in registers: 32 per thread
  unsigned key[32];
  #pragma unroll
  for (int k=0;k<32;++k){
    int i = tid + (k<<10);
    unsigned u = __float_as_uint(d[i]);
    unsigned kk = (u & 0x80000000u) ? ~u : (u|0x80000000u);
    key[k] = (m[i] > 0.f) ? kk : 0xFFFFFFFFu;
  }

  if (tid==0){ s_pre=0u; s_rk=rank; }
  int slice = tid & 15;
  #pragma unroll
  for (int round=0; round<4; ++round){
    const int shift = 24 - 8*round;
    for (int i=tid;i<16*256;i+=OS_T) hist[i]=0;
    __syncthreads();
    unsigned pre = s_pre;
    if (round==0){
      #pragma unroll
      for (int k=0;k<32;++k)
        atomicAdd(&hist[slice*256 + (key[k]>>24)], 1);
    } else {
      #pragma unroll
      for (int k=0;k<32;++k)
        if ((key[k]>>(shift+8)) == pre)
          atomicAdd(&hist[slice*256 + ((key[k]>>shift)&255u)], 1);
    }
    __syncthreads();
    if (tid<256){
      int tt=0;
      #pragma unroll
      for (int s=0;s<16;++s) tt += hist[s*256+tid];
      cum[tid]=tt;
    }
    __syncthreads();
    if (tid<64){
      int c0=cum[4*tid+0],c1=cum[4*tid+1],c2=cum[4*tid+2],c3=cum[4*tid+3];
      int i0=c0, i1=i0+c1, i2=i1+c2, i3=i2+c3;
      int tot=i3, scan=tot;
      #pragma unroll
      for (int off=1;off<64;off<<=1){ int v=__shfl_up(scan,off); if (tid>=off) scan+=v; }
      int base = scan-tot;
      int rk = s_rk; unsigned pr = s_pre;
      int b0=base, b1=base+i0, b2=base+i1, b3=base+i2, e3=base+i3;
      if      (rk>=b0 && rk<b1){ s_pre=(pr<<8)|(unsigned)(4*tid+0); s_rk=rk-b0; }
      else if (rk>=b1 && rk<b2){ s_pre=(pr<<8)|(unsigned)(4*tid+1); s_rk=rk-b1; }
      else if (rk>=b2 && rk<b3){ s_pre=(pr<<8)|(unsigned)(4*tid+2); s_rk=rk-b2; }
      else if (rk>=b3 && rk<e3){ s_pre=(pr<<8)|(unsigned)(4*tid+3); s_rk=rk-b3; }
    }
    __syncthreads();
  }
  if (tid==0){
    unsigned k = s_pre;
    unsigned u = (k & 0x80000000u) ? (k & 0x7FFFFFFFu) : ~k;
    stats[img*16 + 1 + r] = __uint_as_float(u);
    if (r==0) stats[img*16] = (float)cnt;
  }
}

// ---------- K4: per-batch scalar params from order stats ----------
__global__ void k_params(const float* __restrict__ statsE, const float* __restrict__ statsC,
                         float* __restrict__ params){
  int b = threadIdx.x;
  if (b>=NB) return;
  float* pr = params + b*32;
  for (int n=0;n<NA;++n){
    const float* sE = statsE + (size_t)(b*NA+n)*16;
    const float* sC = statsC + (size_t)(b*NA+n)*16;
    int cE=(int)sE[0], cC=(int)sC[0];
    pr[n]    = quantv(cE,0.2f,sE[1],sE[2]);
    pr[5+n]  = quantv(cE,0.8f,sE[3],sE[4]);
    pr[10+n] = quantv(cC,0.2f,sC[1],sC[2]);
    pr[15+n] = quantv(cC,0.8f,sC[3],sC[4]);
  }
  const float* sE0 = statsE + (size_t)(b*NA)*16;
  const float* sC0 = statsC + (size_t)(b*NA)*16;
  float loe=pr[0], hie=pr[5], loc=pr[10], hic=pr[15];
  float de_lo=0.f,de_hi=0.f,ke=0.f, dc_lo=0.f,dc_hi=0.f,kc=0.f;
  int c0=(int)sE0[0];
  if (c0>0){
    int cm1=c0-1;
    float pos2=0.2f*(float)cm1, pos8=0.8f*(float)cm1;
    float f2=pos2-floorf(pos2), f8=pos8-floorf(pos8);
    float a,bb;
    a=1.f-ge_f(sE0[5],loe,hie); bb=1.f-ge_f(sE0[6],loe,hie); de_lo=a+f2*(bb-a);
    a=1.f-ge_f(sE0[7],loe,hie); bb=1.f-ge_f(sE0[8],loe,hie); de_hi=a+f8*(bb-a);
    a=ge_f(sE0[1],loe,hie);     bb=ge_f(sE0[2],loe,hie);     ke  =a+f2*(bb-a);
  }
  int c0c=(int)sC0[0];
  if (c0c>0){
    int cm1=c0c-1;
    float pos2=0.2f*(float)cm1, pos8=0.8f*(float)cm1;
    float f2=pos2-floorf(pos2), f8=pos8-floorf(pos8);
    float a,bb;
    a=1.f-ge_f(sC0[5],loc,hic); bb=1.f-ge_f(sC0[6],loc,hic); dc_lo=a+f2*(bb-a);
    a=1.f-ge_f(sC0[7],loc,hic); bb=1.f-ge_f(sC0[8],loc,hic); dc_hi=a+f8*(bb-a);
    a=ge_f(sC0[1],loc,hic);     bb=ge_f(sC0[2],loc,hic);     kc  =a+f2*(bb-a);
  }
  pr[20]=de_lo; pr[21]=de_hi; pr[22]=dc_lo; pr[23]=dc_hi; pr[24]=ke; pr[25]=kc;
}

// ---------- K5: pattern-gate P (pre-normalization) ----------
__global__ __launch_bounds__(256) void k_ppre(
  const float* __restrict__ vis, const float* __restrict__ scraw,
  const float* __restrict__ energy, const float* __restrict__ params,
  float* __restrict__ ppre)
{
  int w=threadIdx.x, h=blockIdx.x, b=blockIdx.y;
  int p=h*W_+w;
  const float* pr = params + b*32;
  size_t base = (size_t)b*NA*HW_ + p;
  float se[NA], sc[NA], vf[NA];
  #pragma unroll
  for (int n=0;n<NA;++n){
    float vv = vis[base + (size_t)n*HW_];
    float f = (vv>0.f)?1.f:0.f; vf[n]=f;
    se[n] = clip01((energy[base+(size_t)n*HW_]-pr[n])/(pr[5+n]-pr[n]+EPS_))*f;
    sc[n] = clip01((scraw[base+(size_t)n*HW_]-pr[10+n])/(pr[15+n]-pr[10+n]+EPS_))*f;
  }
  float sup = 0.f;
  #pragma unroll
  for (int n=1;n<NA;++n) sup += (0.8f*se[n]+0.2f*sc[n])*vf[n];
  sup *= 0.25f;
  float de = clip01(((1.f-se[0])-pr[20])/(pr[21]-pr[20]+EPS_))*vf[0];
  float dc = clip01(((1.f-sc[0])-pr[22])/(pr[23]-pr[22]+EPS_))*vf[0];
  float D  = (0.7f*de + 0.3f*dc)*vf[0];
  bool ke = (se[0] <= pr[24]) && (vf[0]>0.f);
  bool kc = (sc[0] <= pr[25]) && (vf[0]>0.f);
  float kem = (ke&&kc)?1.f:0.f;
  ppre[(size_t)b*HW_+p] = D*sup*(1.f-kem);
}

// ---------- K6: winner argmax + owner/comm bits ----------
__global__ __launch_bounds__(256) void k_owner(
  const float* __restrict__ vis, const float* __restrict__ scraw,
  const float* __restrict__ sfull, const float* __restrict__ ppre,
  const float* __restrict__ statsP, int* __restrict__ omask)
{
  int w=threadIdx.x,h=blockIdx.x,b=blockIdx.y;
  int p=h*W_+w;
  const float* sP = statsP + b*16;
  int cntP=(int)sP[0];
  float plo = quantv(cntP,0.2f,sP[1],sP[2]);
  float phi = quantv(cntP,0.8f,sP[3],sP[4]);
  size_t base=(size_t)b*NA*HW_+p;
  float vf0 = (vis[base]>0.f)?1.f:0.f;
  float Pf = clip01((ppre[(size_t)b*HW_+p]-plo)/(phi-plo+EPS_))*vf0;
  float gate = 0.1f + 0.9f*Pf;
  int winner=0; float best=-1.f;
  int cbits=0;
  #pragma unroll
  for (int n=0;n<NA;++n){
    float vv = vis[base+(size_t)n*HW_];
    float f=(vv>0.f)?1.f:0.f;
    float s = ((sfull[base+(size_t)n*HW_]*f)*gate)*f;
    if (s>best){best=s;winner=n;}
    bool cm = (n==0) || (scraw[base+(size_t)n*HW_] > 0.5f);
    if (cm) cbits |= 1<<n;
  }
  int ob = ((cbits>>winner)&1) ? (1<<winner) : 0;
  omask[(size_t)b*HW_+p] = ob | (cbits<<8);
}

// ---------- K7: 3x3 dilation, final mask, effective-rate count ----------
__global__ __launch_bounds__(256) void k_final(
  const int* __restrict__ omask, int* __restrict__ fmask, int* __restrict__ counter)
{
  int w=threadIdx.x,h=blockIdx.x,b=blockIdx.y;
  int p=h*W_+w;
  const int* om = omask + (size_t)b*HW_;
  int ow=0;
  #pragma unroll
  for (int dy=-1;dy<=1;++dy){
    int y=h+dy; if (y<0||y>=H_) continue;
    #pragma unroll
    for (int dx=-1;dx<=1;++dx){
      int x=w+dx; if (x<0||x>=W_) continue;
      ow |= om[y*W_+x];
    }
  }
  int cbits=(om[p]>>8)&31;
  int fin = ow & cbits & 31;
  fmask[(size_t)b*HW_+p]=fin;
  int cn = __popc(fin & 30);
  for (int off=32;off;off>>=1) cn += __shfl_down(cn,off);
  if ((threadIdx.x&63)==0) atomicAdd(counter, cn);
}

// ---------- K8: masked-max warped output + effective rate ----------
__global__ __launch_bounds__(256) void k_out(
  const float* __restrict__ x, const float* __restrict__ nam,
  const int* __restrict__ fmask, const int* __restrict__ counter,
  float* __restrict__ out, int out_size)
{
  int w=threadIdx.x, h=blockIdx.x, b=blockIdx.y;
  int p=h*W_+w;
  int fin = fmask[(size_t)b*HW_+p] & 31;
  float init = (__popc(fin)<NA) ? 0.f : -__builtin_inff();
  float m[NC];
  #pragma unroll
  for (int c=0;c<NC;++c) m[c]=init;
  #pragma unroll
  for (int n=0;n<NA;++n){
    if (!((fin>>n)&1)) continue;
    Taps t = make_taps(nam + (size_t)(b*NA*NA+n)*6, h, w);
    const float* xb = x + (size_t)(b*NA+n)*NC*HW_;
    #pragma unroll 8
    for (int c=0;c<NC;++c){
      const float* pc = xb + (size_t)c*HW_;
      float v = t.w00*pc[t.o00] + t.w01*pc[t.o01] + t.w10*pc[t.o10] + t.w11*pc[t.o11];
      m[c] = fmaxf(m[c], v);
    }
  }
  #pragma unroll
  for (int c=0;c<NC;++c) out[(((size_t)b*NC+c)*H_+h)*W_+w] = m[c];
  if (b==0 && h==0 && w==0)
    out[out_size-1] = (float)(*counter) * (1.0f/524288.0f);  // /(B*(N-1)*H*W)
}

extern "C" void kernel_launch(void* const* d_in, const int* in_sizes, int n_in,
                              void* d_out, int out_size, void* d_ws, size_t ws_size,
                              hipStream_t stream) {
  (void)in_sizes; (void)n_in; (void)ws_size;
  const float* x   = (const float*)d_in[0];
  const float* psm = (const float*)d_in[1];
  const float* nam = (const float*)d_in[3];
  float* out = (float*)d_out;

  float* ws     = (float*)d_ws;
  float* vis    = ws;                         // 20*HW
  float* scraw  = vis    + (size_t)NIMG*HW_;  // 20*HW
  float* sfull  = scraw  + (size_t)NIMG*HW_;  // 20*HW
  float* energy = sfull  + (size_t)NIMG*HW_;  // 20*HW
  float* ppre   = energy + (size_t)NIMG*HW_;  // 4*HW
  float* statsE = ppre   + (size_t)NB*HW_;    // 20*16
  float* statsC = statsE + NIMG*16;           // 20*16
  float* statsP = statsC + NIMG*16;           // 4*16
  float* params = statsP + NB*16;             // 4*32
  int*   omask  = (int*)(params + NB*32);     // 4*HW
  int*   fmask  = omask + (size_t)NB*HW_;     // 4*HW
  int*   counter= fmask + (size_t)NB*HW_;     // 1 (+ NIMG vis-counts)
  int*   cntv   = counter + 1;                // 20

  hipLaunchKernelGGL(k_init, dim3(1), dim3(64), 0, stream, counter);
  hipLaunchKernelGGL(k_warp_stats, dim3(H_,NIMG), dim3(W_), 0, stream,
                     x, psm, nam, vis, scraw, sfull, energy, cntv);
  hipLaunchKernelGGL(k_select, dim3(192), dim3(OS_T), 0, stream,
                     energy, scraw, ppre, vis, cntv, statsE, statsC, statsP, 0);
  hipLaunchKernelGGL(k_params, dim3(1), dim3(64), 0, stream, statsE, statsC, params);
  hipLaunchKernelGGL(k_ppre, dim3(H_,NB), dim3(W_), 0, stream,
                     vis, scraw, energy, params, ppre);
  hipLaunchKernelGGL(k_select, dim3(16), dim3(OS_T), 0, stream,
                     energy, scraw, ppre, vis, cntv, statsE, statsC, statsP, 1);
  hipLaunchKernelGGL(k_owner, dim3(H_,NB), dim3(W_), 0, stream,
                     vis, scraw, sfull, ppre, statsP, omask);
  hipLaunchKernelGGL(k_final, dim3(H_,NB), dim3(W_), 0, stream, omask, fmask, counter);
  hipLaunchKernelGGL(k_out, dim3(H_,NB), dim3(W_), 0, stream,
                     x, nam, fmask, counter, out, out_size);
}

// Round 3
// 284.487 us; speedup vs baseline: 2.4976x; 1.3789x over previous
//
#include <hip/hip_runtime.h>

#define W_    256
#define H_    128
#define HW_   32768
#define NB    4
#define NA    5
#define NC    64
#define NIMG  20
#define EPS_  1e-6f

// ---------- bilinear warp taps (matches reference affine_grid + grid_sample) ----------
struct Taps { int o00,o01,o10,o11; float w00,w01,w10,w11; };

__device__ inline Taps make_taps(const float* __restrict__ M, int h, int w){
  float gx = 2.0f*((float)w+0.5f)/(float)W_ - 1.0f;
  float gy = 2.0f*((float)h+0.5f)/(float)H_ - 1.0f;
  float X = M[0]*gx + M[1]*gy + M[2];
  float Y = M[3]*gx + M[4]*gy + M[5];
  float px = ((X+1.0f)*(float)W_ - 1.0f)*0.5f;
  float py = ((Y+1.0f)*(float)H_ - 1.0f)*0.5f;
  float x0f = floorf(px), y0f = floorf(py);
  float wx1 = px-x0f, wy1 = py-y0f;
  float wx0 = 1.0f-wx1, wy0 = 1.0f-wy1;
  int x0=(int)x0f, y0=(int)y0f, x1=x0+1, y1=y0+1;
  bool vx0=(x0>=0)&&(x0<W_), vx1=(x1>=0)&&(x1<W_);
  bool vy0=(y0>=0)&&(y0<H_), vy1=(y1>=0)&&(y1<H_);
  int cx0=min(max(x0,0),W_-1), cx1=min(max(x1,0),W_-1);
  int cy0=min(max(y0,0),H_-1), cy1=min(max(y1,0),H_-1);
  Taps t;
  t.o00=cy0*W_+cx0; t.o01=cy0*W_+cx1; t.o10=cy1*W_+cx0; t.o11=cy1*W_+cx1;
  t.w00=(vy0&&vx0)?(wy0*wx0):0.f;
  t.w01=(vy0&&vx1)?(wy0*wx1):0.f;
  t.w10=(vy1&&vx0)?(wy1*wx0):0.f;
  t.w11=(vy1&&vx1)?(wy1*wx1):0.f;
  return t;
}

__device__ inline float clip01(float v){ return fminf(fmaxf(v,0.f),1.f); }
__device__ inline float sigmoidf_(float v){
  if (v>=0.f){ float e=expf(-v); return 1.f/(1.f+e); }
  float e=expf(v); return e/(1.f+e);
}
__device__ inline float quantv(int cnt, float q, float vlo, float vhi){
  if (cnt<=0) return 0.f;
  float pos = q*(float)(cnt-1);
  float frac = pos - floorf(pos);
  return vlo + frac*(vhi-vlo);
}
__device__ inline float ge_f(float t, float lo, float hi){
  return clip01((t-lo)/(hi-lo+EPS_));
}

// ---------- K0: zero counters (effective-rate + per-image visible counts) ----------
__global__ void k_init(int* counters){ if (threadIdx.x < 1+NIMG) counters[threadIdx.x] = 0; }

// ---------- K1: fused warp of ones/psm/x -> vis, scraw, sfull, energy, vis-counts ----------
// Channel loop batched x16: 64 independent gather loads in flight per thread (MLP).
__global__ __launch_bounds__(256) void k_warp_stats(
  const float* __restrict__ x, const float* __restrict__ psm, const float* __restrict__ nam,
  float* __restrict__ vis, float* __restrict__ scraw, float* __restrict__ sfull,
  float* __restrict__ energy, int* __restrict__ cntv)
{
  int w = threadIdx.x, h = blockIdx.x, bn = blockIdx.y;
  int b = bn/NA, n = bn - b*NA;
  Taps t = make_taps(nam + (size_t)(b*NA*NA + n)*6, h, w);     // M = nam[b,0,n]
  float vv = t.w00 + t.w01 + t.w10 + t.w11;                    // warp of ones
  const float* p0 = psm + ((size_t)bn*2+0)*HW_;
  const float* p1 = psm + ((size_t)bn*2+1)*HW_;
  float c0 = t.w00*p0[t.o00] + t.w01*p0[t.o01] + t.w10*p0[t.o10] + t.w11*p0[t.o11];
  float c1 = t.w00*p1[t.o00] + t.w01*p1[t.o01] + t.w10*p1[t.o10] + t.w11*p1[t.o11];
  float sr = fmaxf(sigmoidf_(c0), sigmoidf_(c1));
  float sf = (clip01(c0)+clip01(c1))*0.5f;
  const float* xb = x + (size_t)bn*NC*HW_;
  float acc = 0.f;
  #pragma unroll 1
  for (int cb=0; cb<NC/16; ++cb){
    const float* pc = xb + (size_t)(cb*16)*HW_;
    float a00[16],a01[16],a10[16],a11[16];
    #pragma unroll
    for (int c=0;c<16;++c){
      a00[c]=pc[t.o00]; a01[c]=pc[t.o01]; a10[c]=pc[t.o10]; a11[c]=pc[t.o11];
      pc += HW_;
    }
    #pragma unroll
    for (int c=0;c<16;++c){
      float v = t.w00*a00[c] + t.w01*a01[c] + t.w10*a10[c] + t.w11*a11[c];
      acc += v*v;
    }
  }
  size_t idx = (size_t)bn*HW_ + h*W_ + w;
  vis[idx]=vv; scraw[idx]=sr; sfull[idx]=sf; energy[idx]=acc*(1.0f/64.0f);
  int vf = (vv>0.f)?1:0;
  #pragma unroll
  for (int off=32;off;off>>=1) vf += __shfl_down(vf,off);
  if ((w&63)==0) atomicAdd(&cntv[bn], vf);
}

// ---------- K3: radix-select, ONE BLOCK PER (image, rank) task ----------
#define OS_T 1024
__global__ __launch_bounds__(1024) void k_select(
    const float* __restrict__ energy, const float* __restrict__ scraw,
    const float* __restrict__ ppre, const float* __restrict__ vis,
    const int* __restrict__ cnts,
    float* __restrict__ statsE, float* __restrict__ statsC, float* __restrict__ statsP,
    int mode)
{
  __shared__ int hist[16*256];
  __shared__ int cum[256];
  __shared__ unsigned s_pre;
  __shared__ int s_rk;
  int tid = threadIdx.x;
  int t = blockIdx.x;

  const float* d; const float* m; float* stats; int img, r, cnt;
  if (mode==0){
    bool isC = (t>=96); int tt = isC ? t-96 : t;
    if (tt<80){ img=tt>>2; r=tt&3; } else { int j=tt-80; img=(j>>2)*NA; r=4+(j&3); }
    d = (isC?scraw:energy) + (size_t)img*HW_;
    m = vis + (size_t)img*HW_;
    stats = isC?statsC:statsE;
    cnt = cnts[img];
  } else {
    img = t>>2; r = t&3;
    d = ppre + (size_t)img*HW_;
    m = vis + (size_t)(img*NA)*HW_;
    stats = statsP;
    cnt = cnts[img*NA];
  }
  int cm1 = cnt>0 ? cnt-1 : 0;
  float p2 = 0.2f*(float)cm1, p8 = 0.8f*(float)cm1;
  int l2=(int)floorf(p2), h2=(int)ceilf(p2), l8=(int)floorf(p8), h8=(int)ceilf(p8);
  int rank;
  switch(r){
    case 0: rank=l2; break;      case 1: rank=h2; break;
    case 2: rank=l8; break;      case 3: rank=h8; break;
    case 4: rank=cm1-l2; break;  case 5: rank=cm1-h2; break;
    case 6: rank=cm1-l8; break;  default: rank=cm1-h8; break;
  }

  unsigned key[32];
  #pragma unroll
  for (int k=0;k<32;++k){
    int i = tid + (k<<10);
    unsigned u = __float_as_uint(d[i]);
    unsigned kk = (u & 0x80000000u) ? ~u : (u|0x80000000u);
    key[k] = (m[i] > 0.f) ? kk : 0xFFFFFFFFu;
  }

  if (tid==0){ s_pre=0u; s_rk=rank; }
  int slice = tid & 15;
  #pragma unroll
  for (int round=0; round<4; ++round){
    const int shift = 24 - 8*round;
    for (int i=tid;i<16*256;i+=OS_T) hist[i]=0;
    __syncthreads();
    unsigned pre = s_pre;
    if (round==0){
      #pragma unroll
      for (int k=0;k<32;++k)
        atomicAdd(&hist[slice*256 + (key[k]>>24)], 1);
    } else {
      #pragma unroll
      for (int k=0;k<32;++k)
        if ((key[k]>>(shift+8)) == pre)
          atomicAdd(&hist[slice*256 + ((key[k]>>shift)&255u)], 1);
    }
    __syncthreads();
    if (tid<256){
      int tt=0;
      #pragma unroll
      for (int s=0;s<16;++s) tt += hist[s*256+tid];
      cum[tid]=tt;
    }
    __syncthreads();
    if (tid<64){
      int c0=cum[4*tid+0],c1=cum[4*tid+1],c2=cum[4*tid+2],c3=cum[4*tid+3];
      int i0=c0, i1=i0+c1, i2=i1+c2, i3=i2+c3;
      int tot=i3, scan=tot;
      #pragma unroll
      for (int off=1;off<64;off<<=1){ int v=__shfl_up(scan,off); if (tid>=off) scan+=v; }
      int base = scan-tot;
      int rk = s_rk; unsigned pr = s_pre;
      int b0=base, b1=base+i0, b2=base+i1, b3=base+i2, e3=base+i3;
      if      (rk>=b0 && rk<b1){ s_pre=(pr<<8)|(unsigned)(4*tid+0); s_rk=rk-b0; }
      else if (rk>=b1 && rk<b2){ s_pre=(pr<<8)|(unsigned)(4*tid+1); s_rk=rk-b1; }
      else if (rk>=b2 && rk<b3){ s_pre=(pr<<8)|(unsigned)(4*tid+2); s_rk=rk-b2; }
      else if (rk>=b3 && rk<e3){ s_pre=(pr<<8)|(unsigned)(4*tid+3); s_rk=rk-b3; }
    }
    __syncthreads();
  }
  if (tid==0){
    unsigned k = s_pre;
    unsigned u = (k & 0x80000000u) ? (k & 0x7FFFFFFFu) : ~k;
    stats[img*16 + 1 + r] = __uint_as_float(u);
    if (r==0) stats[img*16] = (float)cnt;
  }
}

// ---------- K4: per-batch scalar params from order stats ----------
__global__ void k_params(const float* __restrict__ statsE, const float* __restrict__ statsC,
                         float* __restrict__ params){
  int b = threadIdx.x;
  if (b>=NB) return;
  float* pr = params + b*32;
  for (int n=0;n<NA;++n){
    const float* sE = statsE + (size_t)(b*NA+n)*16;
    const float* sC = statsC + (size_t)(b*NA+n)*16;
    int cE=(int)sE[0], cC=(int)sC[0];
    pr[n]    = quantv(cE,0.2f,sE[1],sE[2]);
    pr[5+n]  = quantv(cE,0.8f,sE[3],sE[4]);
    pr[10+n] = quantv(cC,0.2f,sC[1],sC[2]);
    pr[15+n] = quantv(cC,0.8f,sC[3],sC[4]);
  }
  const float* sE0 = statsE + (size_t)(b*NA)*16;
  const float* sC0 = statsC + (size_t)(b*NA)*16;
  float loe=pr[0], hie=pr[5], loc=pr[10], hic=pr[15];
  float de_lo=0.f,de_hi=0.f,ke=0.f, dc_lo=0.f,dc_hi=0.f,kc=0.f;
  int c0=(int)sE0[0];
  if (c0>0){
    int cm1=c0-1;
    float pos2=0.2f*(float)cm1, pos8=0.8f*(float)cm1;
    float f2=pos2-floorf(pos2), f8=pos8-floorf(pos8);
    float a,bb;
    a=1.f-ge_f(sE0[5],loe,hie); bb=1.f-ge_f(sE0[6],loe,hie); de_lo=a+f2*(bb-a);
    a=1.f-ge_f(sE0[7],loe,hie); bb=1.f-ge_f(sE0[8],loe,hie); de_hi=a+f8*(bb-a);
    a=ge_f(sE0[1],loe,hie);     bb=ge_f(sE0[2],loe,hie);     ke  =a+f2*(bb-a);
  }
  int c0c=(int)sC0[0];
  if (c0c>0){
    int cm1=c0c-1;
    float pos2=0.2f*(float)cm1, pos8=0.8f*(float)cm1;
    float f2=pos2-floorf(pos2), f8=pos8-floorf(pos8);
    float a,bb;
    a=1.f-ge_f(sC0[5],loc,hic); bb=1.f-ge_f(sC0[6],loc,hic); dc_lo=a+f2*(bb-a);
    a=1.f-ge_f(sC0[7],loc,hic); bb=1.f-ge_f(sC0[8],loc,hic); dc_hi=a+f8*(bb-a);
    a=ge_f(sC0[1],loc,hic);     bb=ge_f(sC0[2],loc,hic);     kc  =a+f2*(bb-a);
  }
  pr[20]=de_lo; pr[21]=de_hi; pr[22]=dc_lo; pr[23]=dc_hi; pr[24]=ke; pr[25]=kc;
}

// ---------- K5: pattern-gate P (pre-normalization) ----------
__global__ __launch_bounds__(256) void k_ppre(
  const float* __restrict__ vis, const float* __restrict__ scraw,
  const float* __restrict__ energy, const float* __restrict__ params,
  float* __restrict__ ppre)
{
  int w=threadIdx.x, h=blockIdx.x, b=blockIdx.y;
  int p=h*W_+w;
  const float* pr = params + b*32;
  size_t base = (size_t)b*NA*HW_ + p;
  float se[NA], sc[NA], vf[NA];
  #pragma unroll
  for (int n=0;n<NA;++n){
    float vv = vis[base + (size_t)n*HW_];
    float f = (vv>0.f)?1.f:0.f; vf[n]=f;
    se[n] = clip01((energy[base+(size_t)n*HW_]-pr[n])/(pr[5+n]-pr[n]+EPS_))*f;
    sc[n] = clip01((scraw[base+(size_t)n*HW_]-pr[10+n])/(pr[15+n]-pr[10+n]+EPS_))*f;
  }
  float sup = 0.f;
  #pragma unroll
  for (int n=1;n<NA;++n) sup += (0.8f*se[n]+0.2f*sc[n])*vf[n];
  sup *= 0.25f;
  float de = clip01(((1.f-se[0])-pr[20])/(pr[21]-pr[20]+EPS_))*vf[0];
  float dc = clip01(((1.f-sc[0])-pr[22])/(pr[23]-pr[22]+EPS_))*vf[0];
  float D  = (0.7f*de + 0.3f*dc)*vf[0];
  bool ke = (se[0] <= pr[24]) && (vf[0]>0.f);
  bool kc = (sc[0] <= pr[25]) && (vf[0]>0.f);
  float kem = (ke&&kc)?1.f:0.f;
  ppre[(size_t)b*HW_+p] = D*sup*(1.f-kem);
}

// ---------- K6: winner argmax + owner/comm bits ----------
__global__ __launch_bounds__(256) void k_owner(
  const float* __restrict__ vis, const float* __restrict__ scraw,
  const float* __restrict__ sfull, const float* __restrict__ ppre,
  const float* __restrict__ statsP, int* __restrict__ omask)
{
  int w=threadIdx.x,h=blockIdx.x,b=blockIdx.y;
  int p=h*W_+w;
  const float* sP = statsP + b*16;
  int cntP=(int)sP[0];
  float plo = quantv(cntP,0.2f,sP[1],sP[2]);
  float phi = quantv(cntP,0.8f,sP[3],sP[4]);
  size_t base=(size_t)b*NA*HW_+p;
  float vf0 = (vis[base]>0.f)?1.f:0.f;
  float Pf = clip01((ppre[(size_t)b*HW_+p]-plo)/(phi-plo+EPS_))*vf0;
  float gate = 0.1f + 0.9f*Pf;
  int winner=0; float best=-1.f;
  int cbits=0;
  #pragma unroll
  for (int n=0;n<NA;++n){
    float vv = vis[base+(size_t)n*HW_];
    float f=(vv>0.f)?1.f:0.f;
    float s = ((sfull[base+(size_t)n*HW_]*f)*gate)*f;
    if (s>best){best=s;winner=n;}
    bool cm = (n==0) || (scraw[base+(size_t)n*HW_] > 0.5f);
    if (cm) cbits |= 1<<n;
  }
  int ob = ((cbits>>winner)&1) ? (1<<winner) : 0;
  omask[(size_t)b*HW_+p] = ob | (cbits<<8);
}

// ---------- K7: 3x3 dilation, final mask, effective-rate count ----------
__global__ __launch_bounds__(256) void k_final(
  const int* __restrict__ omask, int* __restrict__ fmask, int* __restrict__ counter)
{
  int w=threadIdx.x,h=blockIdx.x,b=blockIdx.y;
  int p=h*W_+w;
  const int* om = omask + (size_t)b*HW_;
  int ow=0;
  #pragma unroll
  for (int dy=-1;dy<=1;++dy){
    int y=h+dy; if (y<0||y>=H_) continue;
    #pragma unroll
    for (int dx=-1;dx<=1;++dx){
      int x=w+dx; if (x<0||x>=W_) continue;
      ow |= om[y*W_+x];
    }
  }
  int cbits=(om[p]>>8)&31;
  int fin = ow & cbits & 31;
  fmask[(size_t)b*HW_+p]=fin;
  int cn = __popc(fin & 30);
  for (int off=32;off;off>>=1) cn += __shfl_down(cn,off);
  if ((threadIdx.x&63)==0) atomicAdd(counter, cn);
}

// ---------- K8: masked-max warped output + effective rate ----------
// Per-16-channel blocks; taps hoisted; 64 gather loads in flight per active agent.
__global__ __launch_bounds__(256) void k_out(
  const float* __restrict__ x, const float* __restrict__ nam,
  const int* __restrict__ fmask, const int* __restrict__ counter,
  float* __restrict__ out, int out_size)
{
  int w=threadIdx.x, h=blockIdx.x, b=blockIdx.y;
  int p=h*W_+w;
  int fin = fmask[(size_t)b*HW_+p] & 31;
  float init = (__popc(fin)<NA) ? 0.f : -__builtin_inff();
  Taps tp[NA];
  #pragma unroll
  for (int n=0;n<NA;++n) tp[n] = make_taps(nam + (size_t)(b*NA*NA+n)*6, h, w);
  #pragma unroll 1
  for (int cb=0; cb<NC/16; ++cb){
    float m[16];
    #pragma unroll
    for (int c=0;c<16;++c) m[c]=init;
    #pragma unroll
    for (int n=0;n<NA;++n){
      if (!((fin>>n)&1)) continue;
      const float* pc = x + ((size_t)(b*NA+n)*NC + cb*16)*HW_;
      float a00[16],a01[16],a10[16],a11[16];
      #pragma unroll
      for (int c=0;c<16;++c){
        a00[c]=pc[tp[n].o00]; a01[c]=pc[tp[n].o01]; a10[c]=pc[tp[n].o10]; a11[c]=pc[tp[n].o11];
        pc += HW_;
      }
      #pragma unroll
      for (int c=0;c<16;++c){
        float v = tp[n].w00*a00[c] + tp[n].w01*a01[c] + tp[n].w10*a10[c] + tp[n].w11*a11[c];
        m[c] = fmaxf(m[c], v);
      }
    }
    #pragma unroll
    for (int c=0;c<16;++c)
      out[(((size_t)b*NC + cb*16 + c)*H_+h)*W_+w] = m[c];
  }
  if (b==0 && h==0 && w==0)
    out[out_size-1] = (float)(*counter) * (1.0f/524288.0f);  // /(B*(N-1)*H*W)
}

extern "C" void kernel_launch(void* const* d_in, const int* in_sizes, int n_in,
                              void* d_out, int out_size, void* d_ws, size_t ws_size,
                              hipStream_t stream) {
  (void)in_sizes; (void)n_in; (void)ws_size;
  const float* x   = (const float*)d_in[0];
  const float* psm = (const float*)d_in[1];
  const float* nam = (const float*)d_in[3];
  float* out = (float*)d_out;

  float* ws     = (float*)d_ws;
  float* vis    = ws;                         // 20*HW
  float* scraw  = vis    + (size_t)NIMG*HW_;  // 20*HW
  float* sfull  = scraw  + (size_t)NIMG*HW_;  // 20*HW
  float* energy = sfull  + (size_t)NIMG*HW_;  // 20*HW
  float* ppre   = energy + (size_t)NIMG*HW_;  // 4*HW
  float* statsE = ppre   + (size_t)NB*HW_;    // 20*16
  float* statsC = statsE + NIMG*16;           // 20*16
  float* statsP = statsC + NIMG*16;           // 4*16
  float* params = statsP + NB*16;             // 4*32
  int*   omask  = (int*)(params + NB*32);     // 4*HW
  int*   fmask  = omask + (size_t)NB*HW_;     // 4*HW
  int*   counter= fmask + (size_t)NB*HW_;     // 1 (+ NIMG vis-counts)
  int*   cntv   = counter + 1;                // 20

  hipLaunchKernelGGL(k_init, dim3(1), dim3(64), 0, stream, counter);
  hipLaunchKernelGGL(k_warp_stats, dim3(H_,NIMG), dim3(W_), 0, stream,
                     x, psm, nam, vis, scraw, sfull, energy, cntv);
  hipLaunchKernelGGL(k_select, dim3(192), dim3(OS_T), 0, stream,
                     energy, scraw, ppre, vis, cntv, statsE, statsC, statsP, 0);
  hipLaunchKernelGGL(k_params, dim3(1), dim3(64), 0, stream, statsE, statsC, params);
  hipLaunchKernelGGL(k_ppre, dim3(H_,NB), dim3(W_), 0, stream,
                     vis, scraw, energy, params, ppre);
  hipLaunchKernelGGL(k_select, dim3(16), dim3(OS_T), 0, stream,
                     energy, scraw, ppre, vis, cntv, statsE, statsC, statsP, 1);
  hipLaunchKernelGGL(k_owner, dim3(H_,NB), dim3(W_), 0, stream,
                     vis, scraw, sfull, ppre, statsP, omask);
  hipLaunchKernelGGL(k_final, dim3(H_,NB), dim3(W_), 0, stream, omask, fmask, counter);
  hipLaunchKernelGGL(k_out, dim3(H_,NB), dim3(W_), 0, stream,
                     x, nam, fmask, counter, out, out_size);
}

// Round 4
// 280.496 us; speedup vs baseline: 2.5331x; 1.0142x over previous
//
#include <hip/hip_runtime.h>

#define W_    256
#define H_    128
#define HW_   32768
#define NB    4
#define NA    5
#define NC    64
#define NIMG  20
#define EPS_  1e-6f

// ---------- bilinear warp taps (matches reference affine_grid + grid_sample) ----------
struct Taps { int o00,o01,o10,o11; float w00,w01,w10,w11; };

__device__ inline Taps make_taps(const float* __restrict__ M, int h, int w){
  float gx = 2.0f*((float)w+0.5f)/(float)W_ - 1.0f;
  float gy = 2.0f*((float)h+0.5f)/(float)H_ - 1.0f;
  float X = M[0]*gx + M[1]*gy + M[2];
  float Y = M[3]*gx + M[4]*gy + M[5];
  float px = ((X+1.0f)*(float)W_ - 1.0f)*0.5f;
  float py = ((Y+1.0f)*(float)H_ - 1.0f)*0.5f;
  float x0f = floorf(px), y0f = floorf(py);
  float wx1 = px-x0f, wy1 = py-y0f;
  float wx0 = 1.0f-wx1, wy0 = 1.0f-wy1;
  int x0=(int)x0f, y0=(int)y0f, x1=x0+1, y1=y0+1;
  bool vx0=(x0>=0)&&(x0<W_), vx1=(x1>=0)&&(x1<W_);
  bool vy0=(y0>=0)&&(y0<H_), vy1=(y1>=0)&&(y1<H_);
  int cx0=min(max(x0,0),W_-1), cx1=min(max(x1,0),W_-1);
  int cy0=min(max(y0,0),H_-1), cy1=min(max(y1,0),H_-1);
  Taps t;
  t.o00=cy0*W_+cx0; t.o01=cy0*W_+cx1; t.o10=cy1*W_+cx0; t.o11=cy1*W_+cx1;
  t.w00=(vy0&&vx0)?(wy0*wx0):0.f;
  t.w01=(vy0&&vx1)?(wy0*wx1):0.f;
  t.w10=(vy1&&vx0)?(wy1*wx0):0.f;
  t.w11=(vy1&&vx1)?(wy1*wx1):0.f;
  return t;
}

__device__ inline float clip01(float v){ return fminf(fmaxf(v,0.f),1.f); }
__device__ inline float sigmoidf_(float v){
  if (v>=0.f){ float e=expf(-v); return 1.f/(1.f+e); }
  float e=expf(v); return e/(1.f+e);
}
__device__ inline float quantv(int cnt, float q, float vlo, float vhi){
  if (cnt<=0) return 0.f;
  float pos = q*(float)(cnt-1);
  float frac = pos - floorf(pos);
  return vlo + frac*(vhi-vlo);
}
__device__ inline float ge_f(float t, float lo, float hi){
  return clip01((t-lo)/(hi-lo+EPS_));
}

// ---------- K0: zero counters (effective-rate + per-image visible counts) ----------
__global__ void k_init(int* counters){ if (threadIdx.x < 1+NIMG) counters[threadIdx.x] = 0; }

// ---------- K1: fused warp of ones/psm/x -> vis, scraw, sfull, energy, vis-counts ----------
// Channel loop batched x32; sched_barrier forces all 128 gathers in flight before use.
// __launch_bounds__(256,2): relax VGPR cap so the scheduler doesn't register-ration.
__global__ __launch_bounds__(256, 2) void k_warp_stats(
  const float* __restrict__ x, const float* __restrict__ psm, const float* __restrict__ nam,
  float* __restrict__ vis, float* __restrict__ scraw, float* __restrict__ sfull,
  float* __restrict__ energy, int* __restrict__ cntv)
{
  int w = threadIdx.x, h = blockIdx.x, bn = blockIdx.y;
  int b = bn/NA, n = bn - b*NA;
  Taps t = make_taps(nam + (size_t)(b*NA*NA + n)*6, h, w);     // M = nam[b,0,n]
  float vv = t.w00 + t.w01 + t.w10 + t.w11;                    // warp of ones
  const float* p0 = psm + ((size_t)bn*2+0)*HW_;
  const float* p1 = psm + ((size_t)bn*2+1)*HW_;
  float c0 = t.w00*p0[t.o00] + t.w01*p0[t.o01] + t.w10*p0[t.o10] + t.w11*p0[t.o11];
  float c1 = t.w00*p1[t.o00] + t.w01*p1[t.o01] + t.w10*p1[t.o10] + t.w11*p1[t.o11];
  float sr = fmaxf(sigmoidf_(c0), sigmoidf_(c1));
  float sf = (clip01(c0)+clip01(c1))*0.5f;
  const float* xb = x + (size_t)bn*NC*HW_;
  float acc = 0.f;
  #pragma unroll 1
  for (int cb=0; cb<NC/32; ++cb){
    const float* pc = xb + (size_t)(cb*32)*HW_;
    float a00[32],a01[32],a10[32],a11[32];
    #pragma unroll
    for (int c=0;c<32;++c){
      a00[c]=pc[t.o00]; a01[c]=pc[t.o01]; a10[c]=pc[t.o10]; a11[c]=pc[t.o11];
      pc += HW_;
    }
    __builtin_amdgcn_sched_barrier(0);   // keep all 128 loads issued before compute
    #pragma unroll
    for (int c=0;c<32;++c){
      float v = t.w00*a00[c] + t.w01*a01[c] + t.w10*a10[c] + t.w11*a11[c];
      acc += v*v;
    }
  }
  size_t idx = (size_t)bn*HW_ + h*W_ + w;
  vis[idx]=vv; scraw[idx]=sr; sfull[idx]=sf; energy[idx]=acc*(1.0f/64.0f);
  int vf = (vv>0.f)?1:0;
  #pragma unroll
  for (int off=32;off;off>>=1) vf += __shfl_down(vf,off);
  if ((w&63)==0) atomicAdd(&cntv[bn], vf);
}

// ---------- K3: radix-select, ONE BLOCK PER (image, rank) task ----------
#define OS_T 1024
__global__ __launch_bounds__(1024) void k_select(
    const float* __restrict__ energy, const float* __restrict__ scraw,
    const float* __restrict__ ppre, const float* __restrict__ vis,
    const int* __restrict__ cnts,
    float* __restrict__ statsE, float* __restrict__ statsC, float* __restrict__ statsP,
    int mode)
{
  __shared__ int hist[16*256];
  __shared__ int cum[256];
  __shared__ unsigned s_pre;
  __shared__ int s_rk;
  int tid = threadIdx.x;
  int t = blockIdx.x;

  const float* d; const float* m; float* stats; int img, r, cnt;
  if (mode==0){
    bool isC = (t>=96); int tt = isC ? t-96 : t;
    if (tt<80){ img=tt>>2; r=tt&3; } else { int j=tt-80; img=(j>>2)*NA; r=4+(j&3); }
    d = (isC?scraw:energy) + (size_t)img*HW_;
    m = vis + (size_t)img*HW_;
    stats = isC?statsC:statsE;
    cnt = cnts[img];
  } else {
    img = t>>2; r = t&3;
    d = ppre + (size_t)img*HW_;
    m = vis + (size_t)(img*NA)*HW_;
    stats = statsP;
    cnt = cnts[img*NA];
  }
  int cm1 = cnt>0 ? cnt-1 : 0;
  float p2 = 0.2f*(float)cm1, p8 = 0.8f*(float)cm1;
  int l2=(int)floorf(p2), h2=(int)ceilf(p2), l8=(int)floorf(p8), h8=(int)ceilf(p8);
  int rank;
  switch(r){
    case 0: rank=l2; break;      case 1: rank=h2; break;
    case 2: rank=l8; break;      case 3: rank=h8; break;
    case 4: rank=cm1-l2; break;  case 5: rank=cm1-h2; break;
    case 6: rank=cm1-l8; break;  default: rank=cm1-h8; break;
  }

  unsigned key[32];
  #pragma unroll
  for (int k=0;k<32;++k){
    int i = tid + (k<<10);
    unsigned u = __float_as_uint(d[i]);
    unsigned kk = (u & 0x80000000u) ? ~u : (u|0x80000000u);
    key[k] = (m[i] > 0.f) ? kk : 0xFFFFFFFFu;
  }

  if (tid==0){ s_pre=0u; s_rk=rank; }
  int slice = tid & 15;
  #pragma unroll
  for (int round=0; round<4; ++round){
    const int shift = 24 - 8*round;
    for (int i=tid;i<16*256;i+=OS_T) hist[i]=0;
    __syncthreads();
    unsigned pre = s_pre;
    if (round==0){
      #pragma unroll
      for (int k=0;k<32;++k)
        atomicAdd(&hist[slice*256 + (key[k]>>24)], 1);
    } else {
      #pragma unroll
      for (int k=0;k<32;++k)
        if ((key[k]>>(shift+8)) == pre)
          atomicAdd(&hist[slice*256 + ((key[k]>>shift)&255u)], 1);
    }
    __syncthreads();
    if (tid<256){
      int tt=0;
      #pragma unroll
      for (int s=0;s<16;++s) tt += hist[s*256+tid];
      cum[tid]=tt;
    }
    __syncthreads();
    if (tid<64){
      int c0=cum[4*tid+0],c1=cum[4*tid+1],c2=cum[4*tid+2],c3=cum[4*tid+3];
      int i0=c0, i1=i0+c1, i2=i1+c2, i3=i2+c3;
      int tot=i3, scan=tot;
      #pragma unroll
      for (int off=1;off<64;off<<=1){ int v=__shfl_up(scan,off); if (tid>=off) scan+=v; }
      int base = scan-tot;
      int rk = s_rk; unsigned pr = s_pre;
      int b0=base, b1=base+i0, b2=base+i1, b3=base+i2, e3=base+i3;
      if      (rk>=b0 && rk<b1){ s_pre=(pr<<8)|(unsigned)(4*tid+0); s_rk=rk-b0; }
      else if (rk>=b1 && rk<b2){ s_pre=(pr<<8)|(unsigned)(4*tid+1); s_rk=rk-b1; }
      else if (rk>=b2 && rk<b3){ s_pre=(pr<<8)|(unsigned)(4*tid+2); s_rk=rk-b2; }
      else if (rk>=b3 && rk<e3){ s_pre=(pr<<8)|(unsigned)(4*tid+3); s_rk=rk-b3; }
    }
    __syncthreads();
  }
  if (tid==0){
    unsigned k = s_pre;
    unsigned u = (k & 0x80000000u) ? (k & 0x7FFFFFFFu) : ~k;
    stats[img*16 + 1 + r] = __uint_as_float(u);
    if (r==0) stats[img*16] = (float)cnt;
  }
}

// ---------- K4: per-batch scalar params from order stats ----------
__global__ void k_params(const float* __restrict__ statsE, const float* __restrict__ statsC,
                         float* __restrict__ params){
  int b = threadIdx.x;
  if (b>=NB) return;
  float* pr = params + b*32;
  for (int n=0;n<NA;++n){
    const float* sE = statsE + (size_t)(b*NA+n)*16;
    const float* sC = statsC + (size_t)(b*NA+n)*16;
    int cE=(int)sE[0], cC=(int)sC[0];
    pr[n]    = quantv(cE,0.2f,sE[1],sE[2]);
    pr[5+n]  = quantv(cE,0.8f,sE[3],sE[4]);
    pr[10+n] = quantv(cC,0.2f,sC[1],sC[2]);
    pr[15+n] = quantv(cC,0.8f,sC[3],sC[4]);
  }
  const float* sE0 = statsE + (size_t)(b*NA)*16;
  const float* sC0 = statsC + (size_t)(b*NA)*16;
  float loe=pr[0], hie=pr[5], loc=pr[10], hic=pr[15];
  float de_lo=0.f,de_hi=0.f,ke=0.f, dc_lo=0.f,dc_hi=0.f,kc=0.f;
  int c0=(int)sE0[0];
  if (c0>0){
    int cm1=c0-1;
    float pos2=0.2f*(float)cm1, pos8=0.8f*(float)cm1;
    float f2=pos2-floorf(pos2), f8=pos8-floorf(pos8);
    float a,bb;
    a=1.f-ge_f(sE0[5],loe,hie); bb=1.f-ge_f(sE0[6],loe,hie); de_lo=a+f2*(bb-a);
    a=1.f-ge_f(sE0[7],loe,hie); bb=1.f-ge_f(sE0[8],loe,hie); de_hi=a+f8*(bb-a);
    a=ge_f(sE0[1],loe,hie);     bb=ge_f(sE0[2],loe,hie);     ke  =a+f2*(bb-a);
  }
  int c0c=(int)sC0[0];
  if (c0c>0){
    int cm1=c0c-1;
    float pos2=0.2f*(float)cm1, pos8=0.8f*(float)cm1;
    float f2=pos2-floorf(pos2), f8=pos8-floorf(pos8);
    float a,bb;
    a=1.f-ge_f(sC0[5],loc,hic); bb=1.f-ge_f(sC0[6],loc,hic); dc_lo=a+f2*(bb-a);
    a=1.f-ge_f(sC0[7],loc,hic); bb=1.f-ge_f(sC0[8],loc,hic); dc_hi=a+f8*(bb-a);
    a=ge_f(sC0[1],loc,hic);     bb=ge_f(sC0[2],loc,hic);     kc  =a+f2*(bb-a);
  }
  pr[20]=de_lo; pr[21]=de_hi; pr[22]=dc_lo; pr[23]=dc_hi; pr[24]=ke; pr[25]=kc;
}

// ---------- K5: pattern-gate P (pre-normalization) ----------
__global__ __launch_bounds__(256) void k_ppre(
  const float* __restrict__ vis, const float* __restrict__ scraw,
  const float* __restrict__ energy, const float* __restrict__ params,
  float* __restrict__ ppre)
{
  int w=threadIdx.x, h=blockIdx.x, b=blockIdx.y;
  int p=h*W_+w;
  const float* pr = params + b*32;
  size_t base = (size_t)b*NA*HW_ + p;
  float se[NA], sc[NA], vf[NA];
  #pragma unroll
  for (int n=0;n<NA;++n){
    float vv = vis[base + (size_t)n*HW_];
    float f = (vv>0.f)?1.f:0.f; vf[n]=f;
    se[n] = clip01((energy[base+(size_t)n*HW_]-pr[n])/(pr[5+n]-pr[n]+EPS_))*f;
    sc[n] = clip01((scraw[base+(size_t)n*HW_]-pr[10+n])/(pr[15+n]-pr[10+n]+EPS_))*f;
  }
  float sup = 0.f;
  #pragma unroll
  for (int n=1;n<NA;++n) sup += (0.8f*se[n]+0.2f*sc[n])*vf[n];
  sup *= 0.25f;
  float de = clip01(((1.f-se[0])-pr[20])/(pr[21]-pr[20]+EPS_))*vf[0];
  float dc = clip01(((1.f-sc[0])-pr[22])/(pr[23]-pr[22]+EPS_))*vf[0];
  float D  = (0.7f*de + 0.3f*dc)*vf[0];
  bool ke = (se[0] <= pr[24]) && (vf[0]>0.f);
  bool kc = (sc[0] <= pr[25]) && (vf[0]>0.f);
  float kem = (ke&&kc)?1.f:0.f;
  ppre[(size_t)b*HW_+p] = D*sup*(1.f-kem);
}

// ---------- K6: winner argmax + owner/comm bits ----------
__global__ __launch_bounds__(256) void k_owner(
  const float* __restrict__ vis, const float* __restrict__ scraw,
  const float* __restrict__ sfull, const float* __restrict__ ppre,
  const float* __restrict__ statsP, int* __restrict__ omask)
{
  int w=threadIdx.x,h=blockIdx.x,b=blockIdx.y;
  int p=h*W_+w;
  const float* sP = statsP + b*16;
  int cntP=(int)sP[0];
  float plo = quantv(cntP,0.2f,sP[1],sP[2]);
  float phi = quantv(cntP,0.8f,sP[3],sP[4]);
  size_t base=(size_t)b*NA*HW_+p;
  float vf0 = (vis[base]>0.f)?1.f:0.f;
  float Pf = clip01((ppre[(size_t)b*HW_+p]-plo)/(phi-plo+EPS_))*vf0;
  float gate = 0.1f + 0.9f*Pf;
  int winner=0; float best=-1.f;
  int cbits=0;
  #pragma unroll
  for (int n=0;n<NA;++n){
    float vv = vis[base+(size_t)n*HW_];
    float f=(vv>0.f)?1.f:0.f;
    float s = ((sfull[base+(size_t)n*HW_]*f)*gate)*f;
    if (s>best){best=s;winner=n;}
    bool cm = (n==0) || (scraw[base+(size_t)n*HW_] > 0.5f);
    if (cm) cbits |= 1<<n;
  }
  int ob = ((cbits>>winner)&1) ? (1<<winner) : 0;
  omask[(size_t)b*HW_+p] = ob | (cbits<<8);
}

// ---------- K7: 3x3 dilation, final mask, effective-rate count ----------
__global__ __launch_bounds__(256) void k_final(
  const int* __restrict__ omask, int* __restrict__ fmask, int* __restrict__ counter)
{
  int w=threadIdx.x,h=blockIdx.x,b=blockIdx.y;
  int p=h*W_+w;
  const int* om = omask + (size_t)b*HW_;
  int ow=0;
  #pragma unroll
  for (int dy=-1;dy<=1;++dy){
    int y=h+dy; if (y<0||y>=H_) continue;
    #pragma unroll
    for (int dx=-1;dx<=1;++dx){
      int x=w+dx; if (x<0||x>=W_) continue;
      ow |= om[y*W_+x];
    }
  }
  int cbits=(om[p]>>8)&31;
  int fin = ow & cbits & 31;
  fmask[(size_t)b*HW_+p]=fin;
  int cn = __popc(fin & 30);
  for (int off=32;off;off>>=1) cn += __shfl_down(cn,off);
  if ((threadIdx.x&63)==0) atomicAdd(counter, cn);
}

// ---------- K8: masked-max warped output + effective rate ----------
// Per-16-channel blocks; taps hoisted; relaxed VGPR cap so the compiler can
// hoist next-agent gathers above current-agent compute.
__global__ __launch_bounds__(256, 2) void k_out(
  const float* __restrict__ x, const float* __restrict__ nam,
  const int* __restrict__ fmask, const int* __restrict__ counter,
  float* __restrict__ out, int out_size)
{
  int w=threadIdx.x, h=blockIdx.x, b=blockIdx.y;
  int p=h*W_+w;
  int fin = fmask[(size_t)b*HW_+p] & 31;
  float init = (__popc(fin)<NA) ? 0.f : -__builtin_inff();
  Taps tp[NA];
  #pragma unroll
  for (int n=0;n<NA;++n) tp[n] = make_taps(nam + (size_t)(b*NA*NA+n)*6, h, w);
  #pragma unroll 1
  for (int cb=0; cb<NC/16; ++cb){
    float m[16];
    #pragma unroll
    for (int c=0;c<16;++c) m[c]=init;
    #pragma unroll
    for (int n=0;n<NA;++n){
      if (!((fin>>n)&1)) continue;
      const float* pc = x + ((size_t)(b*NA+n)*NC + cb*16)*HW_;
      float a00[16],a01[16],a10[16],a11[16];
      #pragma unroll
      for (int c=0;c<16;++c){
        a00[c]=pc[tp[n].o00]; a01[c]=pc[tp[n].o01]; a10[c]=pc[tp[n].o10]; a11[c]=pc[tp[n].o11];
        pc += HW_;
      }
      #pragma unroll
      for (int c=0;c<16;++c){
        float v = tp[n].w00*a00[c] + tp[n].w01*a01[c] + tp[n].w10*a10[c] + tp[n].w11*a11[c];
        m[c] = fmaxf(m[c], v);
      }
    }
    #pragma unroll
    for (int c=0;c<16;++c)
      out[(((size_t)b*NC + cb*16 + c)*H_+h)*W_+w] = m[c];
  }
  if (b==0 && h==0 && w==0)
    out[out_size-1] = (float)(*counter) * (1.0f/524288.0f);  // /(B*(N-1)*H*W)
}

extern "C" void kernel_launch(void* const* d_in, const int* in_sizes, int n_in,
                              void* d_out, int out_size, void* d_ws, size_t ws_size,
                              hipStream_t stream) {
  (void)in_sizes; (void)n_in; (void)ws_size;
  const float* x   = (const float*)d_in[0];
  const float* psm = (const float*)d_in[1];
  const float* nam = (const float*)d_in[3];
  float* out = (float*)d_out;

  float* ws     = (float*)d_ws;
  float* vis    = ws;                         // 20*HW
  float* scraw  = vis    + (size_t)NIMG*HW_;  // 20*HW
  float* sfull  = scraw  + (size_t)NIMG*HW_;  // 20*HW
  float* energy = sfull  + (size_t)NIMG*HW_;  // 20*HW
  float* ppre   = energy + (size_t)NIMG*HW_;  // 4*HW
  float* statsE = ppre   + (size_t)NB*HW_;    // 20*16
  float* statsC = statsE + NIMG*16;           // 20*16
  float* statsP = statsC + NIMG*16;           // 4*16
  float* params = statsP + NB*16;             // 4*32
  int*   omask  = (int*)(params + NB*32);     // 4*HW
  int*   fmask  = omask + (size_t)NB*HW_;     // 4*HW
  int*   counter= fmask + (size_t)NB*HW_;     // 1 (+ NIMG vis-counts)
  int*   cntv   = counter + 1;                // 20

  hipLaunchKernelGGL(k_init, dim3(1), dim3(64), 0, stream, counter);
  hipLaunchKernelGGL(k_warp_stats, dim3(H_,NIMG), dim3(W_), 0, stream,
                     x, psm, nam, vis, scraw, sfull, energy, cntv);
  hipLaunchKernelGGL(k_select, dim3(192), dim3(OS_T), 0, stream,
                     energy, scraw, ppre, vis, cntv, statsE, statsC, statsP, 0);
  hipLaunchKernelGGL(k_params, dim3(1), dim3(64), 0, stream, statsE, statsC, params);
  hipLaunchKernelGGL(k_ppre, dim3(H_,NB), dim3(W_), 0, stream,
                     vis, scraw, energy, params, ppre);
  hipLaunchKernelGGL(k_select, dim3(16), dim3(OS_T), 0, stream,
                     energy, scraw, ppre, vis, cntv, statsE, statsC, statsP, 1);
  hipLaunchKernelGGL(k_owner, dim3(H_,NB), dim3(W_), 0, stream,
                     vis, scraw, sfull, ppre, statsP, omask);
  hipLaunchKernelGGL(k_final, dim3(H_,NB), dim3(W_), 0, stream, omask, fmask, counter);
  hipLaunchKernelGGL(k_out, dim3(H_,NB), dim3(W_), 0, stream,
                     x, nam, fmask, counter, out, out_size);
}

// Round 5
// 247.085 us; speedup vs baseline: 2.8756x; 1.1352x over previous
//
#include <hip/hip_runtime.h>

#define W_    256
#define H_    128
#define HW_   32768
#define NB    4
#define NA    5
#define NC    64
#define NIMG  20
#define EPS_  1e-6f

#define TW    32
#define TH    32
#define CAP   3072      // floats per LDS buffer
#define TRIPS 12        // CAP/256, literal in s_waitcnt below

// ---------- bilinear warp taps (matches reference affine_grid + grid_sample) ----------
struct Taps { int o00,o01,o10,o11; float w00,w01,w10,w11; };
struct TapsC { int cy0,cy1,cx0,cx1; float w00,w01,w10,w11; };

__device__ inline TapsC make_taps_c(float M0,float M1,float M2,float M3,float M4,float M5,
                                    int h, int w){
  float gx = 2.0f*((float)w+0.5f)/(float)W_ - 1.0f;
  float gy = 2.0f*((float)h+0.5f)/(float)H_ - 1.0f;
  float X = M0*gx + M1*gy + M2;
  float Y = M3*gx + M4*gy + M5;
  float px = ((X+1.0f)*(float)W_ - 1.0f)*0.5f;
  float py = ((Y+1.0f)*(float)H_ - 1.0f)*0.5f;
  float x0f = floorf(px), y0f = floorf(py);
  float wx1 = px-x0f, wy1 = py-y0f;
  float wx0 = 1.0f-wx1, wy0 = 1.0f-wy1;
  int x0=(int)x0f, y0=(int)y0f, x1=x0+1, y1=y0+1;
  bool vx0=(x0>=0)&&(x0<W_), vx1=(x1>=0)&&(x1<W_);
  bool vy0=(y0>=0)&&(y0<H_), vy1=(y1>=0)&&(y1<H_);
  TapsC t;
  t.cx0=min(max(x0,0),W_-1); t.cx1=min(max(x1,0),W_-1);
  t.cy0=min(max(y0,0),H_-1); t.cy1=min(max(y1,0),H_-1);
  t.w00=(vy0&&vx0)?(wy0*wx0):0.f;
  t.w01=(vy0&&vx1)?(wy0*wx1):0.f;
  t.w10=(vy1&&vx0)?(wy1*wx0):0.f;
  t.w11=(vy1&&vx1)?(wy1*wx1):0.f;
  return t;
}

__device__ inline Taps make_taps(const float* __restrict__ M, int h, int w){
  TapsC c = make_taps_c(M[0],M[1],M[2],M[3],M[4],M[5],h,w);
  Taps t;
  t.o00=c.cy0*W_+c.cx0; t.o01=c.cy0*W_+c.cx1; t.o10=c.cy1*W_+c.cx0; t.o11=c.cy1*W_+c.cx1;
  t.w00=c.w00; t.w01=c.w01; t.w10=c.w10; t.w11=c.w11;
  return t;
}

__device__ inline void proj_pt(float M0,float M1,float M2,float M3,float M4,float M5,
                               int h,int w,float&px,float&py){
  float gx = 2.0f*((float)w+0.5f)/(float)W_ - 1.0f;
  float gy = 2.0f*((float)h+0.5f)/(float)H_ - 1.0f;
  float X = M0*gx + M1*gy + M2;
  float Y = M3*gx + M4*gy + M5;
  px = ((X+1.0f)*(float)W_ - 1.0f)*0.5f;
  py = ((Y+1.0f)*(float)H_ - 1.0f)*0.5f;
}

__device__ inline float clip01(float v){ return fminf(fmaxf(v,0.f),1.f); }
__device__ inline float sigmoidf_(float v){
  if (v>=0.f){ float e=expf(-v); return 1.f/(1.f+e); }
  float e=expf(v); return e/(1.f+e);
}
__device__ inline float quantv(int cnt, float q, float vlo, float vhi){
  if (cnt<=0) return 0.f;
  float pos = q*(float)(cnt-1);
  float frac = pos - floorf(pos);
  return vlo + frac*(vhi-vlo);
}
__device__ inline float ge_f(float t, float lo, float hi){
  return clip01((t-lo)/(hi-lo+EPS_));
}

__device__ inline void gload4(const float* g, float* l){
  __builtin_amdgcn_global_load_lds(
      (const __attribute__((address_space(1))) void*)g,
      (__attribute__((address_space(3))) void*)l, 4, 0, 0);
}
#define SBAR __builtin_amdgcn_sched_barrier(0)

// ---------- K0: zero counters ----------
__global__ void k_init(int* counters){ if (threadIdx.x < 1+NIMG) counters[threadIdx.x] = 0; }

// ---------- K1: LDS-tiled warp+stats ----------
// Block = 32x32 output tile of one image. Per channel, the source bbox is
// streamed into LDS (coalesced global_load_lds, double-buffered, counted vmcnt),
// then the 4-tap interpolation reads LDS. psm/vis computed directly (small).
__global__ __launch_bounds__(256) void k_warp_stats(
  const float* __restrict__ x, const float* __restrict__ psm, const float* __restrict__ nam,
  float* __restrict__ vis, float* __restrict__ scraw, float* __restrict__ sfull,
  float* __restrict__ energy, int* __restrict__ cntv)
{
  __shared__ float smem[2][CAP];
  int tid = threadIdx.x;
  int tx = blockIdx.x, ty = blockIdx.y, bn = blockIdx.z;
  int b = bn/NA, n = bn - b*NA;
  const float* M = nam + (size_t)(b*NA*NA + n)*6;
  float M0=M[0],M1=M[1],M2=M[2],M3=M[3],M4=M[4],M5=M[5];
  int tw0 = tx*TW, th0 = ty*TH;
  int r  = tid>>3;
  int cb = (tid&7)<<2;
  int h  = th0 + r;
  int w0 = tw0 + cb;

  // exact bbox from tile corners (+1 px safety margin each side)
  float pxa,pya,pxb,pyb,pxc,pyc,pxd,pyd;
  proj_pt(M0,M1,M2,M3,M4,M5, th0,      tw0,      pxa,pya);
  proj_pt(M0,M1,M2,M3,M4,M5, th0,      tw0+TW-1, pxb,pyb);
  proj_pt(M0,M1,M2,M3,M4,M5, th0+TH-1, tw0,      pxc,pyc);
  proj_pt(M0,M1,M2,M3,M4,M5, th0+TH-1, tw0+TW-1, pxd,pyd);
  float pxmin=fminf(fminf(pxa,pxb),fminf(pxc,pxd));
  float pxmax=fmaxf(fmaxf(pxa,pxb),fmaxf(pxc,pxd));
  float pymin=fminf(fminf(pya,pyb),fminf(pyc,pyd));
  float pymax=fmaxf(fmaxf(pya,pyb),fmaxf(pyc,pyd));
  int xs = min(max((int)floorf(pxmin)-1, 0), W_-1);
  int xe = min(max((int)floorf(pxmax)+2, 0), W_-1);
  int ys = min(max((int)floorf(pymin)-1, 0), H_-1);
  int ye = min(max((int)floorf(pymax)+2, 0), H_-1);
  int bw = xe-xs+1, bh = ye-ys+1;
  int E  = bh*bw;

  // per-pixel taps (4 px per thread)
  TapsC tc[4];
  #pragma unroll
  for (int k=0;k<4;++k) tc[k] = make_taps_c(M0,M1,M2,M3,M4,M5, h, w0+k);

  size_t idx = (size_t)bn*HW_ + (size_t)h*W_ + w0;
  float acc[4] = {0.f,0.f,0.f,0.f};

  if (E <= CAP){
    unsigned magic = (unsigned)((0x100000000ULL + (unsigned)bw - 1) / (unsigned)bw);
    const float* xb0 = x + (size_t)bn*NC*HW_ + (size_t)ys*W_ + xs;
    auto issue = [&](int ch, int bsel){
      const float* src = xb0 + (size_t)ch*HW_;
      float* dst = &smem[bsel][0];
      #pragma unroll
      for (int k=0;k<TRIPS;++k){
        int j  = tid + (k<<8);
        int jj = min(j, E-1);
        int row = (int)__umulhi((unsigned)jj, magic);
        int col = jj - row*bw;
        gload4(src + (size_t)row*W_ + col, dst + j);
      }
    };
    issue(0,0); issue(1,1);

    // psm / vis / sfull / scraw while first x tiles stream in
    {
      const float* p0 = psm + ((size_t)bn*2+0)*HW_;
      const float* p1 = psm + ((size_t)bn*2+1)*HW_;
      int vsum = 0;
      #pragma unroll
      for (int k=0;k<4;++k){
        TapsC t = tc[k];
        int o00=t.cy0*W_+t.cx0, o01=t.cy0*W_+t.cx1, o10=t.cy1*W_+t.cx0, o11=t.cy1*W_+t.cx1;
        float vv = t.w00+t.w01+t.w10+t.w11;
        float c0 = t.w00*p0[o00]+t.w01*p0[o01]+t.w10*p0[o10]+t.w11*p0[o11];
        float c1 = t.w00*p1[o00]+t.w01*p1[o01]+t.w10*p1[o10]+t.w11*p1[o11];
        vis[idx+k]   = vv;
        scraw[idx+k] = fmaxf(sigmoidf_(c0), sigmoidf_(c1));
        sfull[idx+k] = (clip01(c0)+clip01(c1))*0.5f;
        vsum += (vv>0.f)?1:0;
      }
      #pragma unroll
      for (int off=32;off;off>>=1) vsum += __shfl_down(vsum,off);
      if ((tid&63)==0) atomicAdd(&cntv[bn], vsum);
    }

    // LDS-local tap offsets
    int li00[4],li01[4],li10[4],li11[4];
    #pragma unroll
    for (int k=0;k<4;++k){
      li00[k]=(tc[k].cy0-ys)*bw + (tc[k].cx0-xs);
      li01[k]=(tc[k].cy0-ys)*bw + (tc[k].cx1-xs);
      li10[k]=(tc[k].cy1-ys)*bw + (tc[k].cx0-xs);
      li11[k]=(tc[k].cy1-ys)*bw + (tc[k].cx1-xs);
    }

    for (int c=0;c<NC;++c){
      asm volatile("s_waitcnt vmcnt(12)" ::: "memory"); SBAR;   // TRIPS
      __builtin_amdgcn_s_barrier(); SBAR;
      const float* B = &smem[c&1][0];
      #pragma unroll
      for (int k=0;k<4;++k){
        float v = tc[k].w00*B[li00[k]] + tc[k].w01*B[li01[k]]
                + tc[k].w10*B[li10[k]] + tc[k].w11*B[li11[k]];
        acc[k] += v*v;
      }
      asm volatile("s_waitcnt lgkmcnt(0)" ::: "memory"); SBAR;
      __builtin_amdgcn_s_barrier(); SBAR;
      issue(min(c+2,NC-1), c&1);    // c>=62: harmless dummy re-issue keeps vmcnt math uniform
    }
    asm volatile("s_waitcnt vmcnt(0)" ::: "memory");
  } else {
    // fallback: direct global gather (never taken for these inputs; keeps correctness universal)
    const float* p0 = psm + ((size_t)bn*2+0)*HW_;
    const float* p1 = psm + ((size_t)bn*2+1)*HW_;
    int vsum = 0;
    int go00[4],go01[4],go10[4],go11[4];
    #pragma unroll
    for (int k=0;k<4;++k){
      TapsC t = tc[k];
      go00[k]=t.cy0*W_+t.cx0; go01[k]=t.cy0*W_+t.cx1;
      go10[k]=t.cy1*W_+t.cx0; go11[k]=t.cy1*W_+t.cx1;
      float vv = t.w00+t.w01+t.w10+t.w11;
      float c0 = t.w00*p0[go00[k]]+t.w01*p0[go01[k]]+t.w10*p0[go10[k]]+t.w11*p0[go11[k]];
      float c1 = t.w00*p1[go00[k]]+t.w01*p1[go01[k]]+t.w10*p1[go10[k]]+t.w11*p1[go11[k]];
      vis[idx+k]   = vv;
      scraw[idx+k] = fmaxf(sigmoidf_(c0), sigmoidf_(c1));
      sfull[idx+k] = (clip01(c0)+clip01(c1))*0.5f;
      vsum += (vv>0.f)?1:0;
    }
    #pragma unroll
    for (int off=32;off;off>>=1) vsum += __shfl_down(vsum,off);
    if ((tid&63)==0) atomicAdd(&cntv[bn], vsum);
    const float* xb = x + (size_t)bn*NC*HW_;
    for (int c=0;c<NC;++c){
      const float* pc = xb + (size_t)c*HW_;
      #pragma unroll
      for (int k=0;k<4;++k){
        float v = tc[k].w00*pc[go00[k]] + tc[k].w01*pc[go01[k]]
                + tc[k].w10*pc[go10[k]] + tc[k].w11*pc[go11[k]];
        acc[k] += v*v;
      }
    }
  }
  #pragma unroll
  for (int k=0;k<4;++k) energy[idx+k] = acc[k]*(1.0f/64.0f);
}

// ---------- K3: radix-select, ONE BLOCK PER (image, rank) task ----------
#define OS_T 1024
__global__ __launch_bounds__(1024) void k_select(
    const float* __restrict__ energy, const float* __restrict__ scraw,
    const float* __restrict__ ppre, const float* __restrict__ vis,
    const int* __restrict__ cnts,
    float* __restrict__ statsE, float* __restrict__ statsC, float* __restrict__ statsP,
    int mode)
{
  __shared__ int hist[16*256];
  __shared__ int cum[256];
  __shared__ unsigned s_pre;
  __shared__ int s_rk;
  int tid = threadIdx.x;
  int t = blockIdx.x;

  const float* d; const float* m; float* stats; int img, r, cnt;
  if (mode==0){
    bool isC = (t>=96); int tt = isC ? t-96 : t;
    if (tt<80){ img=tt>>2; r=tt&3; } else { int j=tt-80; img=(j>>2)*NA; r=4+(j&3); }
    d = (isC?scraw:energy) + (size_t)img*HW_;
    m = vis + (size_t)img*HW_;
    stats = isC?statsC:statsE;
    cnt = cnts[img];
  } else {
    img = t>>2; r = t&3;
    d = ppre + (size_t)img*HW_;
    m = vis + (size_t)(img*NA)*HW_;
    stats = statsP;
    cnt = cnts[img*NA];
  }
  int cm1 = cnt>0 ? cnt-1 : 0;
  float p2 = 0.2f*(float)cm1, p8 = 0.8f*(float)cm1;
  int l2=(int)floorf(p2), h2=(int)ceilf(p2), l8=(int)floorf(p8), h8=(int)ceilf(p8);
  int rank;
  switch(r){
    case 0: rank=l2; break;      case 1: rank=h2; break;
    case 2: rank=l8; break;      case 3: rank=h8; break;
    case 4: rank=cm1-l2; break;  case 5: rank=cm1-h2; break;
    case 6: rank=cm1-l8; break;  default: rank=cm1-h8; break;
  }

  unsigned key[32];
  #pragma unroll
  for (int k=0;k<32;++k){
    int i = tid + (k<<10);
    unsigned u = __float_as_uint(d[i]);
    unsigned kk = (u & 0x80000000u) ? ~u : (u|0x80000000u);
    key[k] = (m[i] > 0.f) ? kk : 0xFFFFFFFFu;
  }

  if (tid==0){ s_pre=0u; s_rk=rank; }
  int slice = tid & 15;
  #pragma unroll
  for (int round=0; round<4; ++round){
    const int shift = 24 - 8*round;
    for (int i=tid;i<16*256;i+=OS_T) hist[i]=0;
    __syncthreads();
    unsigned pre = s_pre;
    if (round==0){
      #pragma unroll
      for (int k=0;k<32;++k)
        atomicAdd(&hist[slice*256 + (key[k]>>24)], 1);
    } else {
      #pragma unroll
      for (int k=0;k<32;++k)
        if ((key[k]>>(shift+8)) == pre)
          atomicAdd(&hist[slice*256 + ((key[k]>>shift)&255u)], 1);
    }
    __syncthreads();
    if (tid<256){
      int tt=0;
      #pragma unroll
      for (int s=0;s<16;++s) tt += hist[s*256+tid];
      cum[tid]=tt;
    }
    __syncthreads();
    if (tid<64){
      int c0=cum[4*tid+0],c1=cum[4*tid+1],c2=cum[4*tid+2],c3=cum[4*tid+3];
      int i0=c0, i1=i0+c1, i2=i1+c2, i3=i2+c3;
      int tot=i3, scan=tot;
      #pragma unroll
      for (int off=1;off<64;off<<=1){ int v=__shfl_up(scan,off); if (tid>=off) scan+=v; }
      int base = scan-tot;
      int rk = s_rk; unsigned pr = s_pre;
      int b0=base, b1=base+i0, b2=base+i1, b3=base+i2, e3=base+i3;
      if      (rk>=b0 && rk<b1){ s_pre=(pr<<8)|(unsigned)(4*tid+0); s_rk=rk-b0; }
      else if (rk>=b1 && rk<b2){ s_pre=(pr<<8)|(unsigned)(4*tid+1); s_rk=rk-b1; }
      else if (rk>=b2 && rk<b3){ s_pre=(pr<<8)|(unsigned)(4*tid+2); s_rk=rk-b2; }
      else if (rk>=b3 && rk<e3){ s_pre=(pr<<8)|(unsigned)(4*tid+3); s_rk=rk-b3; }
    }
    __syncthreads();
  }
  if (tid==0){
    unsigned k = s_pre;
    unsigned u = (k & 0x80000000u) ? (k & 0x7FFFFFFFu) : ~k;
    stats[img*16 + 1 + r] = __uint_as_float(u);
    if (r==0) stats[img*16] = (float)cnt;
  }
}

// ---------- K4: per-batch scalar params from order stats ----------
__global__ void k_params(const float* __restrict__ statsE, const float* __restrict__ statsC,
                         float* __restrict__ params){
  int b = threadIdx.x;
  if (b>=NB) return;
  float* pr = params + b*32;
  for (int n=0;n<NA;++n){
    const float* sE = statsE + (size_t)(b*NA+n)*16;
    const float* sC = statsC + (size_t)(b*NA+n)*16;
    int cE=(int)sE[0], cC=(int)sC[0];
    pr[n]    = quantv(cE,0.2f,sE[1],sE[2]);
    pr[5+n]  = quantv(cE,0.8f,sE[3],sE[4]);
    pr[10+n] = quantv(cC,0.2f,sC[1],sC[2]);
    pr[15+n] = quantv(cC,0.8f,sC[3],sC[4]);
  }
  const float* sE0 = statsE + (size_t)(b*NA)*16;
  const float* sC0 = statsC + (size_t)(b*NA)*16;
  float loe=pr[0], hie=pr[5], loc=pr[10], hic=pr[15];
  float de_lo=0.f,de_hi=0.f,ke=0.f, dc_lo=0.f,dc_hi=0.f,kc=0.f;
  int c0=(int)sE0[0];
  if (c0>0){
    int cm1=c0-1;
    float pos2=0.2f*(float)cm1, pos8=0.8f*(float)cm1;
    float f2=pos2-floorf(pos2), f8=pos8-floorf(pos8);
    float a,bb;
    a=1.f-ge_f(sE0[5],loe,hie); bb=1.f-ge_f(sE0[6],loe,hie); de_lo=a+f2*(bb-a);
    a=1.f-ge_f(sE0[7],loe,hie); bb=1.f-ge_f(sE0[8],loe,hie); de_hi=a+f8*(bb-a);
    a=ge_f(sE0[1],loe,hie);     bb=ge_f(sE0[2],loe,hie);     ke  =a+f2*(bb-a);
  }
  int c0c=(int)sC0[0];
  if (c0c>0){
    int cm1=c0c-1;
    float pos2=0.2f*(float)cm1, pos8=0.8f*(float)cm1;
    float f2=pos2-floorf(pos2), f8=pos8-floorf(pos8);
    float a,bb;
    a=1.f-ge_f(sC0[5],loc,hic); bb=1.f-ge_f(sC0[6],loc,hic); dc_lo=a+f2*(bb-a);
    a=1.f-ge_f(sC0[7],loc,hic); bb=1.f-ge_f(sC0[8],loc,hic); dc_hi=a+f8*(bb-a);
    a=ge_f(sC0[1],loc,hic);     bb=ge_f(sC0[2],loc,hic);     kc  =a+f2*(bb-a);
  }
  pr[20]=de_lo; pr[21]=de_hi; pr[22]=dc_lo; pr[23]=dc_hi; pr[24]=ke; pr[25]=kc;
}

// ---------- K5: pattern-gate P (pre-normalization) ----------
__global__ __launch_bounds__(256) void k_ppre(
  const float* __restrict__ vis, const float* __restrict__ scraw,
  const float* __restrict__ energy, const float* __restrict__ params,
  float* __restrict__ ppre)
{
  int w=threadIdx.x, h=blockIdx.x, b=blockIdx.y;
  int p=h*W_+w;
  const float* pr = params + b*32;
  size_t base = (size_t)b*NA*HW_ + p;
  float se[NA], sc[NA], vf[NA];
  #pragma unroll
  for (int n=0;n<NA;++n){
    float vv = vis[base + (size_t)n*HW_];
    float f = (vv>0.f)?1.f:0.f; vf[n]=f;
    se[n] = clip01((energy[base+(size_t)n*HW_]-pr[n])/(pr[5+n]-pr[n]+EPS_))*f;
    sc[n] = clip01((scraw[base+(size_t)n*HW_]-pr[10+n])/(pr[15+n]-pr[10+n]+EPS_))*f;
  }
  float sup = 0.f;
  #pragma unroll
  for (int n=1;n<NA;++n) sup += (0.8f*se[n]+0.2f*sc[n])*vf[n];
  sup *= 0.25f;
  float de = clip01(((1.f-se[0])-pr[20])/(pr[21]-pr[20]+EPS_))*vf[0];
  float dc = clip01(((1.f-sc[0])-pr[22])/(pr[23]-pr[22]+EPS_))*vf[0];
  float D  = (0.7f*de + 0.3f*dc)*vf[0];
  bool ke = (se[0] <= pr[24]) && (vf[0]>0.f);
  bool kc = (sc[0] <= pr[25]) && (vf[0]>0.f);
  float kem = (ke&&kc)?1.f:0.f;
  ppre[(size_t)b*HW_+p] = D*sup*(1.f-kem);
}

// ---------- K6: winner argmax + owner/comm bits ----------
__global__ __launch_bounds__(256) void k_owner(
  const float* __restrict__ vis, const float* __restrict__ scraw,
  const float* __restrict__ sfull, const float* __restrict__ ppre,
  const float* __restrict__ statsP, int* __restrict__ omask)
{
  int w=threadIdx.x,h=blockIdx.x,b=blockIdx.y;
  int p=h*W_+w;
  const float* sP = statsP + b*16;
  int cntP=(int)sP[0];
  float plo = quantv(cntP,0.2f,sP[1],sP[2]);
  float phi = quantv(cntP,0.8f,sP[3],sP[4]);
  size_t base=(size_t)b*NA*HW_+p;
  float vf0 = (vis[base]>0.f)?1.f:0.f;
  float Pf = clip01((ppre[(size_t)b*HW_+p]-plo)/(phi-plo+EPS_))*vf0;
  float gate = 0.1f + 0.9f*Pf;
  int winner=0; float best=-1.f;
  int cbits=0;
  #pragma unroll
  for (int n=0;n<NA;++n){
    float vv = vis[base+(size_t)n*HW_];
    float f=(vv>0.f)?1.f:0.f;
    float s = ((sfull[base+(size_t)n*HW_]*f)*gate)*f;
    if (s>best){best=s;winner=n;}
    bool cm = (n==0) || (scraw[base+(size_t)n*HW_] > 0.5f);
    if (cm) cbits |= 1<<n;
  }
  int ob = ((cbits>>winner)&1) ? (1<<winner) : 0;
  omask[(size_t)b*HW_+p] = ob | (cbits<<8);
}

// ---------- K7: 3x3 dilation, final mask, effective-rate count ----------
__global__ __launch_bounds__(256) void k_final(
  const int* __restrict__ omask, int* __restrict__ fmask, int* __restrict__ counter)
{
  int w=threadIdx.x,h=blockIdx.x,b=blockIdx.y;
  int p=h*W_+w;
  const int* om = omask + (size_t)b*HW_;
  int ow=0;
  #pragma unroll
  for (int dy=-1;dy<=1;++dy){
    int y=h+dy; if (y<0||y>=H_) continue;
    #pragma unroll
    for (int dx=-1;dx<=1;++dx){
      int x=w+dx; if (x<0||x>=W_) continue;
      ow |= om[y*W_+x];
    }
  }
  int cbits=(om[p]>>8)&31;
  int fin = ow & cbits & 31;
  fmask[(size_t)b*HW_+p]=fin;
  int cn = __popc(fin & 30);
  for (int off=32;off;off>>=1) cn += __shfl_down(cn,off);
  if ((threadIdx.x&63)==0) atomicAdd(counter, cn);
}

// ---------- K8: masked-max warped output + effective rate ----------
__global__ __launch_bounds__(256, 2) void k_out(
  const float* __restrict__ x, const float* __restrict__ nam,
  const int* __restrict__ fmask, const int* __restrict__ counter,
  float* __restrict__ out, int out_size)
{
  int w=threadIdx.x, h=blockIdx.x, b=blockIdx.y;
  int p=h*W_+w;
  int fin = fmask[(size_t)b*HW_+p] & 31;
  float init = (__popc(fin)<NA) ? 0.f : -__builtin_inff();
  Taps tp[NA];
  #pragma unroll
  for (int n=0;n<NA;++n) tp[n] = make_taps(nam + (size_t)(b*NA*NA+n)*6, h, w);
  #pragma unroll 1
  for (int cb=0; cb<NC/16; ++cb){
    float m[16];
    #pragma unroll
    for (int c=0;c<16;++c) m[c]=init;
    #pragma unroll
    for (int n=0;n<NA;++n){
      if (!((fin>>n)&1)) continue;
      const float* pc = x + ((size_t)(b*NA+n)*NC + cb*16)*HW_;
      float a00[16],a01[16],a10[16],a11[16];
      #pragma unroll
      for (int c=0;c<16;++c){
        a00[c]=pc[tp[n].o00]; a01[c]=pc[tp[n].o01]; a10[c]=pc[tp[n].o10]; a11[c]=pc[tp[n].o11];
        pc += HW_;
      }
      #pragma unroll
      for (int c=0;c<16;++c){
        float v = tp[n].w00*a00[c] + tp[n].w01*a01[c] + tp[n].w10*a10[c] + tp[n].w11*a11[c];
        m[c] = fmaxf(m[c], v);
      }
    }
    #pragma unroll
    for (int c=0;c<16;++c)
      out[(((size_t)b*NC + cb*16 + c)*H_+h)*W_+w] = m[c];
  }
  if (b==0 && h==0 && w==0)
    out[out_size-1] = (float)(*counter) * (1.0f/524288.0f);  // /(B*(N-1)*H*W)
}

extern "C" void kernel_launch(void* const* d_in, const int* in_sizes, int n_in,
                              void* d_out, int out_size, void* d_ws, size_t ws_size,
                              hipStream_t stream) {
  (void)in_sizes; (void)n_in; (void)ws_size;
  const float* x   = (const float*)d_in[0];
  const float* psm = (const float*)d_in[1];
  const float* nam = (const float*)d_in[3];
  float* out = (float*)d_out;

  float* ws     = (float*)d_ws;
  float* vis    = ws;                         // 20*HW
  float* scraw  = vis    + (size_t)NIMG*HW_;  // 20*HW
  float* sfull  = scraw  + (size_t)NIMG*HW_;  // 20*HW
  float* energy = sfull  + (size_t)NIMG*HW_;  // 20*HW
  float* ppre   = energy + (size_t)NIMG*HW_;  // 4*HW
  float* statsE = ppre   + (size_t)NB*HW_;    // 20*16
  float* statsC = statsE + NIMG*16;           // 20*16
  float* statsP = statsC + NIMG*16;           // 4*16
  float* params = statsP + NB*16;             // 4*32
  int*   omask  = (int*)(params + NB*32);     // 4*HW
  int*   fmask  = omask + (size_t)NB*HW_;     // 4*HW
  int*   counter= fmask + (size_t)NB*HW_;     // 1 (+ NIMG vis-counts)
  int*   cntv   = counter + 1;                // 20

  hipLaunchKernelGGL(k_init, dim3(1), dim3(64), 0, stream, counter);
  hipLaunchKernelGGL(k_warp_stats, dim3(W_/TW, H_/TH, NIMG), dim3(256), 0, stream,
                     x, psm, nam, vis, scraw, sfull, energy, cntv);
  hipLaunchKernelGGL(k_select, dim3(192), dim3(OS_T), 0, stream,
                     energy, scraw, ppre, vis, cntv, statsE, statsC, statsP, 0);
  hipLaunchKernelGGL(k_params, dim3(1), dim3(64), 0, stream, statsE, statsC, params);
  hipLaunchKernelGGL(k_ppre, dim3(H_,NB), dim3(W_), 0, stream,
                     vis, scraw, energy, params, ppre);
  hipLaunchKernelGGL(k_select, dim3(16), dim3(OS_T), 0, stream,
                     energy, scraw, ppre, vis, cntv, statsE, statsC, statsP, 1);
  hipLaunchKernelGGL(k_owner, dim3(H_,NB), dim3(W_), 0, stream,
                     vis, scraw, sfull, ppre, statsP, omask);
  hipLaunchKernelGGL(k_final, dim3(H_,NB), dim3(W_), 0, stream, omask, fmask, counter);
  hipLaunchKernelGGL(k_out, dim3(H_,NB), dim3(W_), 0, stream,
                     x, nam, fmask, counter, out, out_size);
}